// Round 8
// baseline (505.426 us; speedup 1.0000x reference)
//
#include <hip/hip_runtime.h>

#define HID 128
#define CHUNK 3072      // edges per epart block
#define CAP2 5120       // max edges per 256-node bucket in elocal fast path
#define TH_STRIDE 132   // padded bf16 bounce-row stride (shorts): conflict-free epilogue

typedef __attribute__((ext_vector_type(8))) short bf16x8;
typedef __attribute__((ext_vector_type(4))) float f32x4;
typedef __attribute__((ext_vector_type(2))) float f32x2;

__device__ inline unsigned short f2bf(float f) {
    unsigned u = __float_as_uint(f);
    unsigned r = (u + 0x7fff + ((u >> 16) & 1)) >> 16;
    return (unsigned short)r;
}
__device__ inline float bf2f(unsigned short b) {
    return __uint_as_float(((unsigned)b) << 16);
}
// split v into trunc-bf16 hi (low 16 bits) + trunc-bf16 lo (high 16 bits)
__device__ inline unsigned packhl(float v) {
    unsigned h = __float_as_uint(v) >> 16;
    float lo = v - __uint_as_float(h << 16);
    unsigned l = __float_as_uint(lo) >> 16;
    return h | (l << 16);
}

// packed-pair helpers: map to v_pk_fma_f32 / v_pk_max_f32 on gfx950
__device__ __forceinline__ f32x2 fma2(f32x2 a, f32x2 b, f32x2 c) {
    return __builtin_elementwise_fma(a, b, c);
}
__device__ __forceinline__ f32x2 max2(f32x2 a, f32x2 b) {
    return __builtin_elementwise_max(a, b);
}
// two bf16 cols packed in one uint -> f32 pair
__device__ __forceinline__ f32x2 bf2x2(unsigned pv) {
    f32x2 r;
    r.x = __uint_as_float(pv << 16);
    r.y = __uint_as_float(pv & 0xffff0000u);
    return r;
}

// ===== fused preamble: W hi/lo splits + bnsums/pools zero + dst histogram =====
__global__ __launch_bounds__(256) void fused_pre(
    const float* __restrict__ W12, const float* __restrict__ W21,
    const float* __restrict__ W22, const float* __restrict__ W31,
    const float* __restrict__ W32, unsigned short* __restrict__ wt,
    float* __restrict__ bnsums, float* __restrict__ poolz, long long PZ,
    const int* __restrict__ dst, int* __restrict__ icnt, int E)
{
    int b = blockIdx.x, t = threadIdx.x;
    if (b < 320) {
        int w = b >> 6;
        int idx = (b & 63) * 256 + t;
        const float* W = (w == 0) ? W12 : (w == 1) ? W21 : (w == 2) ? W22 : (w == 3) ? W31 : W32;
        unsigned short* wh = wt + (size_t)w * 32768;
        unsigned short* wl = wh + 16384;
        int n = idx >> 7, k = idx & 127;
        float wv = W[k * 128 + n];
        unsigned short h = (unsigned short)(__float_as_uint(wv) >> 16);
        float lo = wv - bf2f(h);
        unsigned short l = (unsigned short)(__float_as_uint(lo) >> 16);
        wh[idx] = h;
        wl[idx] = l;
    } else if (b == 320) {
        for (int i = t; i < 768; i += 256) bnsums[i] = 0.f;
    } else if (b < 338) {
        long long s0 = (long long)(b - 321) * 16384;
        long long e1 = s0 + 16384; if (e1 > PZ) e1 = PZ;
        for (long long i = s0 + t; i < e1; i += 256) poolz[i] = 0.f;
    } else {
        int stride = (gridDim.x - 338) * 256;
        for (int e = (b - 338) * 256 + t; e < E; e += stride)
            atomicAdd(&icnt[dst[e]], 1);
    }
}

// ================= CSR scan =================
__global__ void scan_block(const int* __restrict__ cnt, int* __restrict__ excl,
                           int* __restrict__ partials, int Nn)
{
    __shared__ int ls[256];
    int i = blockIdx.x * 256 + threadIdx.x;
    int v = (i < Nn) ? cnt[i] : 0;
    ls[threadIdx.x] = v;
    __syncthreads();
    for (int off = 1; off < 256; off <<= 1) {
        int t = (threadIdx.x >= off) ? ls[threadIdx.x - off] : 0;
        __syncthreads();
        ls[threadIdx.x] += t;
        __syncthreads();
    }
    if (i < Nn) excl[i] = ls[threadIdx.x] - v;
    if (threadIdx.x == 255) partials[blockIdx.x] = ls[255];
}

// per-block redundant partials scan + offsets/bcur write
__global__ void scan_addf(const int* __restrict__ excl, const int* __restrict__ partials,
                          int nb, int* __restrict__ offsets, int* __restrict__ bcur,
                          int Nn, int E)
{
    __shared__ int ls[256];
    int t = threadIdx.x;
    int v = (t < nb) ? partials[t] : 0;
    ls[t] = v;
    __syncthreads();
    for (int off = 1; off < 256; off <<= 1) {
        int x = (t >= off) ? ls[t - off] : 0;
        __syncthreads();
        ls[t] += x;
        __syncthreads();
    }
    int base = (blockIdx.x > 0) ? ls[blockIdx.x - 1] : 0;
    int i = blockIdx.x * 256 + t;
    if (i < Nn) {
        int o = excl[i] + base;
        offsets[i] = o;
        if ((i & 255) == 0) bcur[i >> 8] = o;
    }
    if (blockIdx.x == 0 && t == 0) offsets[Nn] = E;
}

// ===== epart: partition edges into 256-node MSD buckets (index-staged, LDS-light) =====
__global__ __launch_bounds__(256) void epart(
    const int* __restrict__ dst, const int* __restrict__ src,
    const float* __restrict__ ea, int* __restrict__ bcur,
    float4* __restrict__ stage, int* __restrict__ sdst, int E)
{
    __shared__ int dl[CHUNK];              // 12KB: dst value per original k
    __shared__ unsigned short idxl[CHUNK]; // 6KB: original k per sorted slot
    __shared__ int cnt[256], gsl[256], exs[256], scw[256];
    int t = threadIdx.x;
    int e0 = blockIdx.x * CHUNK;
    int n = E - e0; if (n > CHUNK) n = CHUNK;
    cnt[t] = 0;
    __syncthreads();
    for (int k = t; k < n; k += 256) {
        int dv = dst[e0 + k];
        dl[k] = dv;
        atomicAdd(&cnt[dv >> 8], 1);
    }
    __syncthreads();
    int v = cnt[t];
    int gb = 0;
    if (v > 0) gb = atomicAdd(&bcur[t], v);
    gsl[t] = gb;
    scw[t] = v;
    __syncthreads();
    for (int off = 1; off < 256; off <<= 1) {
        int x = (t >= off) ? scw[t - off] : 0;
        __syncthreads();
        scw[t] += x;
        __syncthreads();
    }
    int excl = scw[t] - v;
    exs[t] = excl;
    cnt[t] = excl;              // fill cursor
    __syncthreads();
    for (int k = t; k < n; k += 256) {
        int d = dl[k] >> 8;
        int s = atomicAdd(&cnt[d], 1);
        idxl[s] = (unsigned short)k;
    }
    __syncthreads();
    // writeout: consecutive slots -> consecutive stage addresses per bucket run
    for (int k = t; k < n; k += 256) {
        int kk = idxl[k];
        int dv = dl[kk];
        int d = dv >> 8;
        int pos = gsl[d] + (k - exs[d]);
        int e = e0 + kk;
        float4 p;
        p.x = __int_as_float(src[e]);
        p.y = ea[e * 3];
        p.z = ea[e * 3 + 1];
        p.w = ea[e * 3 + 2];
        stage[pos] = p;
        sdst[pos] = dv;
    }
}

// ===== elocal: per-bucket counting sort into final CSR epack (index-staged) =====
__global__ __launch_bounds__(256) void elocal(
    const float4* __restrict__ stage, const int* __restrict__ sdst,
    const int* __restrict__ offsets, float4* __restrict__ epack, int Nn)
{
    __shared__ unsigned short idxl[CAP2];  // 10KB
    __shared__ unsigned char  ldc[CAP2];   // 5KB: local dst (0..255)
    __shared__ int cnt[256], exs[256], noff[256], scw[256];
    int t = threadIdx.x;
    int b = blockIdx.x;
    int nbeg = b << 8;
    int nend = nbeg + 256; if (nend > Nn) nend = Nn;
    int beg = offsets[nbeg];
    int end = offsets[nend];
    int n = end - beg;
    noff[t] = (nbeg + t < Nn) ? offsets[nbeg + t] : 0;
    cnt[t] = 0;
    __syncthreads();
    if (n <= CAP2) {
        for (int k = t; k < n; k += 256) {
            int d = sdst[beg + k] & 255;
            ldc[k] = (unsigned char)d;
            atomicAdd(&cnt[d], 1);
        }
        __syncthreads();
        int v = cnt[t];
        scw[t] = v;
        __syncthreads();
        for (int off = 1; off < 256; off <<= 1) {
            int x = (t >= off) ? scw[t - off] : 0;
            __syncthreads();
            scw[t] += x;
            __syncthreads();
        }
        int excl = scw[t] - v;
        exs[t] = excl;
        cnt[t] = excl;          // fill cursor
        __syncthreads();
        for (int k = t; k < n; k += 256) {
            int d = ldc[k];
            int s = atomicAdd(&cnt[d], 1);
            idxl[s] = (unsigned short)k;
        }
        __syncthreads();
        for (int k = t; k < n; k += 256) {
            int kk = idxl[k];
            int d = ldc[kk];
            int pos = noff[d] + (k - exs[d]);
            epack[pos] = stage[beg + kk];   // gathered read (L2-hot), linear-run write
        }
    } else {
        for (int k = t; k < n; k += 256) {
            int d = sdst[beg + k] & 255;
            int r = atomicAdd(&cnt[d], 1);
            epack[noff[d] + r] = stage[beg + k];
        }
    }
}

// ================= layer 1: CSR gather (dim 7), 4-deep pipelined =================
__global__ void gather_d7(const float* __restrict__ x, const float4* __restrict__ epack,
                          const int* __restrict__ offsets,
                          const float* __restrict__ We, const float* __restrict__ be,
                          float* __restrict__ agg, int Nn)
{
    int tid = blockIdx.x * blockDim.x + threadIdx.x;
    int node = tid >> 3;
    int c = tid & 7;
    if (node >= Nn) return;
    float w0 = 0.f, w1 = 0.f, w2 = 0.f, b = 0.f;
    if (c < 7) { w0 = We[c]; w1 = We[7 + c]; w2 = We[14 + c]; b = be[c]; }
    int beg = offsets[node], end = offsets[node + 1];
    float acc = 0.f;
    int i = beg;
    for (; i + 4 <= end; i += 4) {
        float4 ep[4]; float xv[4];
#pragma unroll
        for (int j = 0; j < 4; ++j) ep[j] = epack[i + j];
#pragma unroll
        for (int j = 0; j < 4; ++j)
            xv[j] = (c < 7) ? x[__float_as_int(ep[j].x) * 7 + c] : 0.f;
#pragma unroll
        for (int j = 0; j < 4; ++j) {
            float v = b + xv[j];
            v = fmaf(ep[j].y, w0, v);
            v = fmaf(ep[j].z, w1, v);
            v = fmaf(ep[j].w, w2, v);
            acc += fmaxf(v, 0.f);
        }
    }
    int rem = end - i;
    if (rem > 0) {
        float4 ep[4]; float xv[4];
#pragma unroll
        for (int j = 0; j < 4; ++j) if (j < rem) ep[j] = epack[i + j];
#pragma unroll
        for (int j = 0; j < 4; ++j) if (j < rem)
            xv[j] = (c < 7) ? x[__float_as_int(ep[j].x) * 7 + c] : 0.f;
#pragma unroll
        for (int j = 0; j < 4; ++j) if (j < rem) {
            float v = b + xv[j];
            v = fmaf(ep[j].y, w0, v);
            v = fmaf(ep[j].z, w1, v);
            v = fmaf(ep[j].w, w2, v);
            acc += fmaxf(v, 0.f);
        }
    }
    if (c < 7) agg[node * 7 + c] = acc;
}

// ====== per-node GINE gather (r6-proven loop): returns acc + BN-relu self term ======
__device__ __forceinline__ f32x2 gine_gather_node(
    const unsigned short* __restrict__ h16,
    const float4* __restrict__ epack,
    int beg, int end, int node, int lane,
    f32x2 w0, f32x2 w1, f32x2 w2, f32x2 bb, f32x2 aa, f32x2 ab)
{
    const f32x2 zero2 = {0.f, 0.f};
    f32x2 acc2 = zero2;
    int i = beg;
    for (; i + 8 <= end; i += 8) {
        float4 e[8];
        unsigned p[8];
#pragma unroll
        for (int j = 0; j < 8; ++j) e[j] = epack[i + j];
#pragma unroll
        for (int j = 0; j < 8; ++j)
            p[j] = ((const unsigned*)(h16 + (size_t)__float_as_int(e[j].x) * HID))[lane];
#pragma unroll
        for (int j = 0; j < 8; ++j) {
            f32x2 hb = max2(fma2(bf2x2(p[j]), aa, ab), zero2);   // BN + relu (prev layer)
            f32x2 v = hb + bb;
            f32x2 ey = {e[j].y, e[j].y};
            f32x2 ez = {e[j].z, e[j].z};
            f32x2 ew = {e[j].w, e[j].w};
            v = fma2(ey, w0, v);
            v = fma2(ez, w1, v);
            v = fma2(ew, w2, v);
            acc2 += max2(v, zero2);                               // message relu + sum
        }
    }
    int rem = end - i;        // wave-uniform
    if (rem > 0) {
        float4 e[8];
        unsigned p[8];
#pragma unroll
        for (int j = 0; j < 8; ++j) if (j < rem) e[j] = epack[i + j];
#pragma unroll
        for (int j = 0; j < 8; ++j) if (j < rem)
            p[j] = ((const unsigned*)(h16 + (size_t)__float_as_int(e[j].x) * HID))[lane];
#pragma unroll
        for (int j = 0; j < 8; ++j) if (j < rem) {
            f32x2 hb = max2(fma2(bf2x2(p[j]), aa, ab), zero2);
            f32x2 v = hb + bb;
            f32x2 ey = {e[j].y, e[j].y};
            f32x2 ez = {e[j].z, e[j].z};
            f32x2 ew = {e[j].w, e[j].w};
            v = fma2(ey, w0, v);
            v = fma2(ez, w1, v);
            v = fma2(ew, w2, v);
            acc2 += max2(v, zero2);
        }
    }
    // self term: BN+relu of own pre-BN row
    unsigned hv = ((const unsigned*)(h16 + (size_t)node * HID))[lane];
    f32x2 sf = max2(fma2(bf2x2(hv), aa, ab), zero2);
    return acc2 + sf;
}

// ===== unpack interleaved hi/lo uint pairs into two bf16x8 via v_perm_b32 =====
__device__ __forceinline__ void unpack_hl(const unsigned* Tp, bf16x8& ah, bf16x8& al)
{
    uint4 pa = *(const uint4*)Tp;
    uint4 pb = *(const uint4*)(Tp + 4);
    union { unsigned u[4]; bf16x8 v; } H, L;
    H.u[0] = __builtin_amdgcn_perm(pa.y, pa.x, 0x05040100u);
    L.u[0] = __builtin_amdgcn_perm(pa.y, pa.x, 0x07060302u);
    H.u[1] = __builtin_amdgcn_perm(pa.w, pa.z, 0x05040100u);
    L.u[1] = __builtin_amdgcn_perm(pa.w, pa.z, 0x07060302u);
    H.u[2] = __builtin_amdgcn_perm(pb.y, pb.x, 0x05040100u);
    L.u[2] = __builtin_amdgcn_perm(pb.y, pb.x, 0x07060302u);
    H.u[3] = __builtin_amdgcn_perm(pb.w, pb.z, 0x05040100u);
    L.u[3] = __builtin_amdgcn_perm(pb.w, pb.z, 0x07060302u);
    ah = H.v;
    al = L.v;
}

// ===== MFMA core (RF row-frags of 16): acc[2][RF] = T @ Wt for this wave's 32 cols =====
template <int RF>
__device__ __forceinline__ void mfma_core_t(
    const unsigned* T,
    const unsigned short* __restrict__ Wh, const unsigned short* __restrict__ Wl,
    const float* __restrict__ bias,
    int wave, int q, int li, f32x4 (&acc)[2][RF])
{
    int ctg0 = wave * 2, ctg1 = wave * 2 + 1;
    float b0 = bias[ctg0 * 16 + li];
    float b1v = bias[ctg1 * 16 + li];
#pragma unroll
    for (int rf = 0; rf < RF; ++rf) {
        acc[0][rf][0] = b0;  acc[0][rf][1] = b0;  acc[0][rf][2] = b0;  acc[0][rf][3] = b0;
        acc[1][rf][0] = b1v; acc[1][rf][1] = b1v; acc[1][rf][2] = b1v; acc[1][rf][3] = b1v;
    }
#pragma unroll
    for (int kb = 0; kb < 4; ++kb) {
        int k0 = kb * 32 + q * 8;
        size_t w0off = (size_t)(ctg0 * 16 + li) * HID + k0;
        size_t w1off = (size_t)(ctg1 * 16 + li) * HID + k0;
        bf16x8 bh0 = *(const bf16x8*)(Wh + w0off);
        bf16x8 bl0 = *(const bf16x8*)(Wl + w0off);
        bf16x8 bh1 = *(const bf16x8*)(Wh + w1off);
        bf16x8 bl1 = *(const bf16x8*)(Wl + w1off);
#pragma unroll
        for (int rf = 0; rf < RF; ++rf) {
            const unsigned* Tp = T + (rf * 16 + li) * 132 + k0;
            bf16x8 ah, al;
            unpack_hl(Tp, ah, al);
            acc[0][rf] = __builtin_amdgcn_mfma_f32_16x16x32_bf16(ah, bh0, acc[0][rf], 0, 0, 0);
            acc[0][rf] = __builtin_amdgcn_mfma_f32_16x16x32_bf16(ah, bl0, acc[0][rf], 0, 0, 0);
            acc[0][rf] = __builtin_amdgcn_mfma_f32_16x16x32_bf16(al, bh0, acc[0][rf], 0, 0, 0);
            acc[1][rf] = __builtin_amdgcn_mfma_f32_16x16x32_bf16(ah, bh1, acc[1][rf], 0, 0, 0);
            acc[1][rf] = __builtin_amdgcn_mfma_f32_16x16x32_bf16(ah, bl1, acc[1][rf], 0, 0, 0);
            acc[1][rf] = __builtin_amdgcn_mfma_f32_16x16x32_bf16(al, bh1, acc[1][rf], 0, 0, 0);
        }
    }
}

// epilogue: h (pre-BN) -> bf16 via padded LDS bounce (conflict-free), stats to bnsums
template <int RF>
__device__ __forceinline__ void epilogue_h16_t(
    f32x4 (&acc)[2][RF], unsigned short* __restrict__ h16g,
    float* __restrict__ bnsums, float* sls, float* slq, unsigned short* Th,
    int node0, int wave, int q, int li, int t, int N)
{
#pragma unroll
    for (int ct = 0; ct < 2; ++ct) {
        int colb = (wave * 2 + ct) * 16 + li;
        float sv = 0.f, qv = 0.f;
#pragma unroll
        for (int rf = 0; rf < RF; ++rf) {
#pragma unroll
            for (int r = 0; r < 4; ++r) {
                int rloc = rf * 16 + q * 4 + r;
                float v = acc[ct][rf][r];
                Th[rloc * TH_STRIDE + colb] = f2bf(v);
                if (node0 + rloc < N) { sv += v; qv = fmaf(v, v, qv); }
            }
        }
        sv += __shfl_down(sv, 16); sv += __shfl_down(sv, 32);
        qv += __shfl_down(qv, 16); qv += __shfl_down(qv, 32);
        if (q == 0) { sls[colb] = sv; slq[colb] = qv; }
    }
    __syncthreads();
    int rows = N - node0; if (rows > RF * 16) rows = RF * 16;
    uint2* dstp = (uint2*)(h16g + (size_t)node0 * HID);
    const uint2* srcp = (const uint2*)Th;        // row stride 33 uint2 (132 shorts)
    for (int i = t; i < rows * 32; i += 256) {
        int row = i >> 5, c = i & 31;
        dstp[i] = srcp[row * 33 + c];
    }
    if (t < 128) {
        atomicAdd(&bnsums[t], sls[t]);
        atomicAdd(&bnsums[128 + t], slq[t]);
    }
}

// ===== fused layers 2/3: gather(+BN of prev) -> LDS -> Lin2(relu(Lin1(.))) -> h16out =====
// 32 nodes/block, 4 waves; wave w gathers nodes w*8..w*8+7 straight into MFMA staging LDS.
// Reads h16in, writes h16out (ping-pong buffers -> no cross-block RAW race).
__global__ __launch_bounds__(256) void gather_mlp(
    const unsigned short* __restrict__ h16in,
    const float4* __restrict__ epack,
    const int* __restrict__ offsets,
    const float* __restrict__ We, const float* __restrict__ be,
    const float* __restrict__ sums, const float* __restrict__ g,
    const float* __restrict__ bt,
    const unsigned short* __restrict__ W1h, const unsigned short* __restrict__ W1l,
    const float* __restrict__ b1,
    const unsigned short* __restrict__ W2h, const unsigned short* __restrict__ W2l,
    const float* __restrict__ b2,
    unsigned short* __restrict__ h16out, float* __restrict__ bnsums_out, int N)
{
    __shared__ unsigned Ta[32 * 132];
    __shared__ unsigned Tb[32 * 132];
    __shared__ __align__(16) float as_[128], bs_[128];
    __shared__ float sls[128], slq[128];
    int t = threadIdx.x;
    int wave = t >> 6, lane = t & 63;
    int q = lane >> 4, li = lane & 15;
    int node0 = blockIdx.x * 32;

    // BN coefficients of the previous layer
    if (t < 128) {
        float inv = 1.f / (float)N;
        float mu = sums[t] * inv;
        float var = sums[128 + t] * inv - mu * mu;
        float rs = rsqrtf(fmaxf(var, 0.f) + 1e-5f);
        float a = g[t] * rs;
        as_[t] = a;
        bs_[t] = bt[t] - a * mu;
    }
    __syncthreads();

    // ---- phase 0: gather 8 nodes per wave straight into Ta (packed hi/lo) ----
    {
        const f32x2* W2 = (const f32x2*)We;
        f32x2 w0 = W2[lane];
        f32x2 w1 = W2[64 + lane];
        f32x2 w2 = W2[128 + lane];
        f32x2 bb = ((const f32x2*)be)[lane];
        f32x2 aa = ((const f32x2*)as_)[lane];
        f32x2 ab = ((const f32x2*)bs_)[lane];
        for (int k = 0; k < 8; ++k) {
            int row = wave * 8 + k;
            int node = node0 + row;
            uint2 ov = {0u, 0u};
            if (node < N) {                      // wave-uniform branch
                int beg = __builtin_amdgcn_readfirstlane(offsets[node]);
                int end = __builtin_amdgcn_readfirstlane(offsets[node + 1]);
                f32x2 r = gine_gather_node(h16in, epack, beg, end, node, lane,
                                           w0, w1, w2, bb, aa, ab);
                ov.x = packhl(r.x);
                ov.y = packhl(r.y);
            }
            *(uint2*)(Ta + row * 132 + 2 * lane) = ov;
        }
    }
    __syncthreads();

    // ---- phase 1: Ta @ W1 -> relu -> packed Tb ----
    {
        f32x4 acc[2][2];
        mfma_core_t<2>(Ta, W1h, W1l, b1, wave, q, li, acc);
#pragma unroll
        for (int ct = 0; ct < 2; ++ct) {
            int colb = (wave * 2 + ct) * 16 + li;
#pragma unroll
            for (int rf = 0; rf < 2; ++rf) {
#pragma unroll
                for (int r = 0; r < 4; ++r) {
                    float v = fmaxf(acc[ct][rf][r], 0.f);
                    Tb[(rf * 16 + q * 4 + r) * 132 + colb] = packhl(v);
                }
            }
        }
    }
    __syncthreads();

    // ---- phase 2: Tb @ W2 -> h16out (+stats); dead Ta reused as bf16 bounce ----
    {
        f32x4 acc[2][2];
        mfma_core_t<2>(Tb, W2h, W2l, b2, wave, q, li, acc);
        epilogue_h16_t<2>(acc, h16out, bnsums_out, sls, slq, (unsigned short*)Ta,
                          node0, wave, q, li, t, N);
    }
}

// ===== fused MLP layer 1: phase-1 K=7 fp32 vector (x+agg7) -> packed Tb, phase-2 MFMA =====
__global__ __launch_bounds__(256) void mlp1_fused(
    const float* __restrict__ x, const float* __restrict__ agg,
    const float* __restrict__ W1, const float* __restrict__ b1,     // [7][128]
    const unsigned short* __restrict__ W2h, const unsigned short* __restrict__ W2l,
    const float* __restrict__ b2,
    unsigned short* __restrict__ h16g, float* __restrict__ bnsums, int N)
{
    __shared__ unsigned Tb[64 * 132];
    __shared__ unsigned short Th[64 * TH_STRIDE];
    __shared__ float sls[128], slq[128];
    int t = threadIdx.x;
    int wave = t >> 6, lane = t & 63;
    int q = lane >> 4, li = lane & 15;
    int node0 = blockIdx.x * 64;

    // phase 1: rows wave*16+li (4 waves cover 64 rows), q covers col-groups of 32
    {
        int row = node0 + wave * 16 + li;
        bool ok = row < N;
        float xa[7];
#pragma unroll
        for (int k = 0; k < 7; ++k) xa[k] = ok ? (x[row * 7 + k] + agg[row * 7 + k]) : 0.f;
        const float4* W14 = (const float4*)W1;
        const float4* b14 = (const float4*)b1;
        unsigned* Trow = Tb + (wave * 16 + li) * 132 + q * 32;
#pragma unroll
        for (int c4 = 0; c4 < 8; ++c4) {
            float4 v = b14[q * 8 + c4];
#pragma unroll
            for (int k = 0; k < 7; ++k) {
                float4 w = W14[k * 32 + q * 8 + c4];
                v.x = fmaf(xa[k], w.x, v.x);
                v.y = fmaf(xa[k], w.y, v.y);
                v.z = fmaf(xa[k], w.z, v.z);
                v.w = fmaf(xa[k], w.w, v.w);
            }
            uint4 pk;
            pk.x = packhl(fmaxf(v.x, 0.f));
            pk.y = packhl(fmaxf(v.y, 0.f));
            pk.z = packhl(fmaxf(v.z, 0.f));
            pk.w = packhl(fmaxf(v.w, 0.f));
            *(uint4*)(Trow + c4 * 4) = pk;
        }
    }
    __syncthreads();

    // phase 2
    {
        f32x4 acc[2][4];
        mfma_core_t<4>(Tb, W2h, W2l, b2, wave, q, li, acc);
        epilogue_h16_t<4>(acc, h16g, bnsums, sls, slq, Th, node0, wave, q, li, t, N);
    }
}

// ===== layer-3 BN-apply + mean-pool from bf16 h16 (batch sorted, segmented) =====
__global__ __launch_bounds__(256) void bn_pool(
    const unsigned short* __restrict__ h16, const float* __restrict__ sums,
    const float* __restrict__ g, const float* __restrict__ bt,
    const int* __restrict__ batch,
    float* __restrict__ pools, float* __restrict__ cnt, int Nn)
{
    __shared__ float as_[128], bs_[128];
    int t = threadIdx.x;
    if (t < 128) {
        float inv = 1.f / (float)Nn;
        float mu = sums[t] * inv;
        float var = sums[128 + t] * inv - mu * mu;
        float rs = rsqrtf(fmaxf(var, 0.f) + 1e-5f);
        float a = g[t] * rs;
        as_[t] = a;
        bs_[t] = bt[t] - a * mu;
    }
    __syncthreads();
    int half = t >> 7;
    int c = t & 127;
    int base = blockIdx.x * 64 + half * 32;
    if (base >= Nn) return;
    int lim = base + 32 < Nn ? base + 32 : Nn;
    int g0 = batch[base];
    float s = 0.f, ncnt = 0.f;
    for (int n = base; n < lim; ++n) {
        int gg = batch[n];
        if (gg != g0) {
            atomicAdd(&pools[(size_t)g0 * HID + c], s);
            if (c == 0) atomicAdd(&cnt[g0], ncnt);
            s = 0.f; ncnt = 0.f; g0 = gg;
        }
        float hraw = bf2f(h16[(size_t)n * HID + c]);
        float v = fmaxf(fmaf(hraw, as_[c], bs_[c]), 0.f);
        s += v;
        ncnt += 1.f;
    }
    atomicAdd(&pools[(size_t)g0 * HID + c], s);
    if (c == 0) atomicAdd(&cnt[g0], ncnt);
}

__global__ void head_kernel(const float* __restrict__ pools, const float* __restrict__ cnt,
                            const float* __restrict__ Wf1, const float* __restrict__ bf1,
                            const float* __restrict__ Wf2, const float* __restrict__ bf2,
                            float* __restrict__ out, int G)
{
    int g = blockIdx.x;
    int t = threadIdx.x;
    __shared__ float p[128];
    float inv = 1.f / fmaxf(cnt[g], 1.f);
    p[t] = pools[g * 128 + t] * inv;
    p[t + 64] = pools[g * 128 + t + 64] * inv;
    __syncthreads();
    float o = bf1[t];
#pragma unroll 8
    for (int k = 0; k < 128; ++k) o = fmaf(p[k], Wf1[k * 64 + t], o);
    o = fmaxf(o, 0.f);
    float prod = o * Wf2[t];
#pragma unroll
    for (int off = 32; off > 0; off >>= 1) prod += __shfl_down(prod, off);
    if (t == 0) out[g] = prod + bf2[0];
}

extern "C" void kernel_launch(void* const* d_in, const int* in_sizes, int n_in,
                              void* d_out, int out_size, void* d_ws, size_t ws_size,
                              hipStream_t stream)
{
    const float* x     = (const float*)d_in[0];
    const float* ea    = (const float*)d_in[1];
    const int*   eidx  = (const int*)d_in[2];
    const int*   batch = (const int*)d_in[3];
    const float* We1 = (const float*)d_in[4];  const float* be1 = (const float*)d_in[5];
    const float* W11 = (const float*)d_in[6];  const float* b11 = (const float*)d_in[7];
    const float* W12 = (const float*)d_in[8];  const float* b12 = (const float*)d_in[9];
    const float* g1  = (const float*)d_in[10]; const float* bt1 = (const float*)d_in[11];
    const float* We2 = (const float*)d_in[12]; const float* be2 = (const float*)d_in[13];
    const float* W21 = (const float*)d_in[14]; const float* b21 = (const float*)d_in[15];
    const float* W22 = (const float*)d_in[16]; const float* b22 = (const float*)d_in[17];
    const float* g2  = (const float*)d_in[18]; const float* bt2 = (const float*)d_in[19];
    const float* We3 = (const float*)d_in[20]; const float* be3 = (const float*)d_in[21];
    const float* W31 = (const float*)d_in[22]; const float* b31 = (const float*)d_in[23];
    const float* W32 = (const float*)d_in[24]; const float* b32 = (const float*)d_in[25];
    const float* g3  = (const float*)d_in[26]; const float* bt3 = (const float*)d_in[27];
    const float* Wf1 = (const float*)d_in[28]; const float* bf1 = (const float*)d_in[29];
    const float* Wf2 = (const float*)d_in[30]; const float* bf2 = (const float*)d_in[31];

    const int N = in_sizes[0] / 7;
    const int E = in_sizes[1] / 3;
    const int G = out_size;
    const int* src = eidx;
    const int* dst = eidx + E;

    float* ws = (float*)d_ws;
    float4* stage    = (float4*)ws;                          // E float4 (sort staging)
    int*    sdst     = (int*)(stage + E);                    // E ints
    unsigned short* h16b = (unsigned short*)(sdst + E);      // N*128 bf16 (ping-pong B)
    float* agg7      = (float*)(h16b + (size_t)N * HID);     // N*7
    float* bnsums    = agg7 + (size_t)N * 7;                 // 3 x 256
    float* pools     = bnsums + 768;                         // G*128
    float* cntp      = pools + (size_t)G * HID;              // G
    size_t fused     = (size_t)(cntp + G - ws);
    fused = (fused + 3) & ~(size_t)3;                        // 16B align for epack
    float4* epack    = (float4*)(ws + fused);                // E float4
    unsigned short* h16 = (unsigned short*)(epack + E);      // N*128 bf16 (ping-pong A)
    int*   icnt      = (int*)(h16 + (size_t)N * HID);        // N
    int*   ioffs     = icnt + N;                             // N+1
    int*   ibcur     = ioffs + N + 1;                        // 256 (bucket slice cursors)
    int*   ipart     = ibcur + 256;                          // 256
    int*   iexcl     = ipart + 256;                          // N
    unsigned short* wt = (unsigned short*)(iexcl + N);       // 5 x 2 x 16384
    unsigned short* w12h = wt;            unsigned short* w12l = wt + 16384;
    unsigned short* w21h = wt + 32768;    unsigned short* w21l = wt + 49152;
    unsigned short* w22h = wt + 65536;    unsigned short* w22l = wt + 81920;
    unsigned short* w31h = wt + 98304;    unsigned short* w31l = wt + 114688;
    unsigned short* w32h = wt + 131072;   unsigned short* w32l = wt + 147456;

    const unsigned grid_mfma = (unsigned)((N + 63) / 64);
    const unsigned grid_gm   = (unsigned)((N + 31) / 32);
    const unsigned nb_scan   = (unsigned)((N + 255) / 256);
    const unsigned grid_gat7 = (unsigned)(((long long)N * 8 + 255) / 256);
    const unsigned grid_pool = (unsigned)((N + 63) / 64);
    const unsigned grid_part = (unsigned)((E + CHUNK - 1) / CHUNK);
    const unsigned grid_buck = (unsigned)((N + 255) / 256);
    const long long PZ = (long long)G * HID + G;

    // ---------- preamble: W splits + zeros + histogram (one launch) ----------
    hipMemsetAsync(icnt, 0, (size_t)N * sizeof(int), stream);
    fused_pre<<<1122, 256, 0, stream>>>(W12, W21, W22, W31, W32, wt,
                                        bnsums, pools, PZ, dst, icnt, E);

    // ---------- CSR offsets + two-phase edge sort ----------
    scan_block<<<nb_scan, 256, 0, stream>>>(icnt, iexcl, ipart, N);
    scan_addf<<<nb_scan, 256, 0, stream>>>(iexcl, ipart, (int)nb_scan, ioffs, ibcur, N, E);
    epart<<<grid_part, 256, 0, stream>>>(dst, src, ea, ibcur, stage, sdst, E);
    elocal<<<grid_buck, 256, 0, stream>>>(stage, sdst, ioffs, epack, N);

    // ---------- layer 1 ----------
    gather_d7<<<grid_gat7, 256, 0, stream>>>(x, epack, ioffs, We1, be1, agg7, N);
    mlp1_fused<<<grid_mfma, 256, 0, stream>>>(x, agg7, W11, b11, w12h, w12l, b12,
                                              h16, bnsums, N);

    // ---------- layer 2 (fused gather+MLP): h16 -> h16b ----------
    gather_mlp<<<grid_gm, 256, 0, stream>>>(h16, epack, ioffs, We2, be2,
                                            bnsums, g1, bt1,
                                            w21h, w21l, b21, w22h, w22l, b22,
                                            h16b, bnsums + 256, N);

    // ---------- layer 3 (fused gather+MLP): h16b -> h16 ----------
    gather_mlp<<<grid_gm, 256, 0, stream>>>(h16b, epack, ioffs, We3, be3,
                                            bnsums + 256, g2, bt2,
                                            w31h, w31l, b31, w32h, w32l, b32,
                                            h16, bnsums + 512, N);

    // ---------- BN-apply + segmented pool + head ----------
    bn_pool<<<grid_pool, 256, 0, stream>>>(h16, bnsums + 512, g3, bt3, batch,
                                           pools, cntp, N);
    head_kernel<<<G, 64, 0, stream>>>(pools, cntp, Wf1, bf1, Wf2, bf2, (float*)d_out, G);
}

// Round 10
// 437.913 us; speedup vs baseline: 1.1542x; 1.1542x over previous
//
#include <hip/hip_runtime.h>

#define HID 128
#define CHUNK 3072      // edges per epart block
#define CAP2 5120       // max edges per 256-node bucket in elocal fast path
#define TH_STRIDE 132   // padded bf16 bounce-row stride (shorts): conflict-free epilogue

typedef __attribute__((ext_vector_type(8))) short bf16x8;
typedef __attribute__((ext_vector_type(4))) float f32x4;
typedef __attribute__((ext_vector_type(2))) float f32x2;
typedef __attribute__((ext_vector_type(2))) unsigned u32x2;

__device__ inline unsigned short f2bf(float f) {
    unsigned u = __float_as_uint(f);
    unsigned r = (u + 0x7fff + ((u >> 16) & 1)) >> 16;
    return (unsigned short)r;
}
__device__ inline float bf2f(unsigned short b) {
    return __uint_as_float(((unsigned)b) << 16);
}
// split v into trunc-bf16 hi (low 16 bits) + trunc-bf16 lo (high 16 bits)
__device__ inline unsigned packhl(float v) {
    unsigned h = __float_as_uint(v) >> 16;
    float lo = v - __uint_as_float(h << 16);
    unsigned l = __float_as_uint(lo) >> 16;
    return h | (l << 16);
}

// packed-pair helpers: map to v_pk_fma_f32 / v_pk_max_f32 on gfx950
__device__ __forceinline__ f32x2 fma2(f32x2 a, f32x2 b, f32x2 c) {
    return __builtin_elementwise_fma(a, b, c);
}
__device__ __forceinline__ f32x2 max2(f32x2 a, f32x2 b) {
    return __builtin_elementwise_max(a, b);
}
// two bf16 cols packed in one uint -> f32 pair (lo short = col x, hi short = col y)
__device__ __forceinline__ f32x2 bf2x2(unsigned pv) {
    f32x2 r;
    r.x = __uint_as_float(pv << 16);
    r.y = __uint_as_float(pv & 0xffff0000u);
    return r;
}

// ===== fused preamble: W hi/lo splits + bnsums/pools zero + dst histogram =====
__global__ __launch_bounds__(256) void fused_pre(
    const float* __restrict__ W12, const float* __restrict__ W21,
    const float* __restrict__ W22, const float* __restrict__ W31,
    const float* __restrict__ W32, unsigned short* __restrict__ wt,
    float* __restrict__ bnsums, float* __restrict__ poolz, long long PZ,
    const int* __restrict__ dst, int* __restrict__ icnt, int E)
{
    int b = blockIdx.x, t = threadIdx.x;
    if (b < 320) {
        int w = b >> 6;
        int idx = (b & 63) * 256 + t;
        const float* W = (w == 0) ? W12 : (w == 1) ? W21 : (w == 2) ? W22 : (w == 3) ? W31 : W32;
        unsigned short* wh = wt + (size_t)w * 32768;
        unsigned short* wl = wh + 16384;
        int n = idx >> 7, k = idx & 127;
        float wv = W[k * 128 + n];
        unsigned short h = (unsigned short)(__float_as_uint(wv) >> 16);
        float lo = wv - bf2f(h);
        unsigned short l = (unsigned short)(__float_as_uint(lo) >> 16);
        wh[idx] = h;
        wl[idx] = l;
    } else if (b == 320) {
        for (int i = t; i < 768; i += 256) bnsums[i] = 0.f;
    } else if (b < 338) {
        long long s0 = (long long)(b - 321) * 16384;
        long long e1 = s0 + 16384; if (e1 > PZ) e1 = PZ;
        for (long long i = s0 + t; i < e1; i += 256) poolz[i] = 0.f;
    } else {
        int stride = (gridDim.x - 338) * 256;
        for (int e = (b - 338) * 256 + t; e < E; e += stride)
            atomicAdd(&icnt[dst[e]], 1);
    }
}

// ================= CSR scan =================
__global__ void scan_block(const int* __restrict__ cnt, int* __restrict__ excl,
                           int* __restrict__ partials, int Nn)
{
    __shared__ int ls[256];
    int i = blockIdx.x * 256 + threadIdx.x;
    int v = (i < Nn) ? cnt[i] : 0;
    ls[threadIdx.x] = v;
    __syncthreads();
    for (int off = 1; off < 256; off <<= 1) {
        int t = (threadIdx.x >= off) ? ls[threadIdx.x - off] : 0;
        __syncthreads();
        ls[threadIdx.x] += t;
        __syncthreads();
    }
    if (i < Nn) excl[i] = ls[threadIdx.x] - v;
    if (threadIdx.x == 255) partials[blockIdx.x] = ls[255];
}

// per-block redundant partials scan + offsets/bcur write (replaces 2 kernels)
__global__ void scan_addf(const int* __restrict__ excl, const int* __restrict__ partials,
                          int nb, int* __restrict__ offsets, int* __restrict__ bcur,
                          int Nn, int E)
{
    __shared__ int ls[256];
    int t = threadIdx.x;
    int v = (t < nb) ? partials[t] : 0;
    ls[t] = v;
    __syncthreads();
    for (int off = 1; off < 256; off <<= 1) {
        int x = (t >= off) ? ls[t - off] : 0;
        __syncthreads();
        ls[t] += x;
        __syncthreads();
    }
    int base = (blockIdx.x > 0) ? ls[blockIdx.x - 1] : 0;
    int i = blockIdx.x * 256 + t;
    if (i < Nn) {
        int o = excl[i] + base;
        offsets[i] = o;
        if ((i & 255) == 0) bcur[i >> 8] = o;
    }
    if (blockIdx.x == 0 && t == 0) offsets[Nn] = E;
}

// ===== epart: partition edges into 256-node MSD buckets (index-staged, LDS-light) =====
__global__ __launch_bounds__(256) void epart(
    const int* __restrict__ dst, const int* __restrict__ src,
    const float* __restrict__ ea, int* __restrict__ bcur,
    float4* __restrict__ stage, int* __restrict__ sdst, int E)
{
    __shared__ int dl[CHUNK];              // 12KB: dst value per original k
    __shared__ unsigned short idxl[CHUNK]; // 6KB: original k per sorted slot
    __shared__ int cnt[256], gsl[256], exs[256], scw[256];
    int t = threadIdx.x;
    int e0 = blockIdx.x * CHUNK;
    int n = E - e0; if (n > CHUNK) n = CHUNK;
    cnt[t] = 0;
    __syncthreads();
    for (int k = t; k < n; k += 256) {
        int dv = dst[e0 + k];
        dl[k] = dv;
        atomicAdd(&cnt[dv >> 8], 1);
    }
    __syncthreads();
    int v = cnt[t];
    int gb = 0;
    if (v > 0) gb = atomicAdd(&bcur[t], v);
    gsl[t] = gb;
    scw[t] = v;
    __syncthreads();
    for (int off = 1; off < 256; off <<= 1) {
        int x = (t >= off) ? scw[t - off] : 0;
        __syncthreads();
        scw[t] += x;
        __syncthreads();
    }
    int excl = scw[t] - v;
    exs[t] = excl;
    cnt[t] = excl;              // fill cursor
    __syncthreads();
    for (int k = t; k < n; k += 256) {
        int d = dl[k] >> 8;
        int s = atomicAdd(&cnt[d], 1);
        idxl[s] = (unsigned short)k;
    }
    __syncthreads();
    // writeout: consecutive slots -> consecutive stage addresses per bucket run
    for (int k = t; k < n; k += 256) {
        int kk = idxl[k];
        int dv = dl[kk];
        int d = dv >> 8;
        int pos = gsl[d] + (k - exs[d]);
        int e = e0 + kk;
        float4 p;
        p.x = __int_as_float(src[e]);
        p.y = ea[e * 3];
        p.z = ea[e * 3 + 1];
        p.w = ea[e * 3 + 2];
        stage[pos] = p;
        sdst[pos] = dv;
    }
}

// ===== elocal: per-bucket counting sort into final CSR epack (index-staged) =====
__global__ __launch_bounds__(256) void elocal(
    const float4* __restrict__ stage, const int* __restrict__ sdst,
    const int* __restrict__ offsets, float4* __restrict__ epack, int Nn)
{
    __shared__ unsigned short idxl[CAP2];  // 10KB
    __shared__ unsigned char  ldc[CAP2];   // 5KB: local dst (0..255)
    __shared__ int cnt[256], exs[256], noff[256], scw[256];
    int t = threadIdx.x;
    int b = blockIdx.x;
    int nbeg = b << 8;
    int nend = nbeg + 256; if (nend > Nn) nend = Nn;
    int beg = offsets[nbeg];
    int end = offsets[nend];
    int n = end - beg;
    noff[t] = (nbeg + t < Nn) ? offsets[nbeg + t] : 0;
    cnt[t] = 0;
    __syncthreads();
    if (n <= CAP2) {
        for (int k = t; k < n; k += 256) {
            int d = sdst[beg + k] & 255;
            ldc[k] = (unsigned char)d;
            atomicAdd(&cnt[d], 1);
        }
        __syncthreads();
        int v = cnt[t];
        scw[t] = v;
        __syncthreads();
        for (int off = 1; off < 256; off <<= 1) {
            int x = (t >= off) ? scw[t - off] : 0;
            __syncthreads();
            scw[t] += x;
            __syncthreads();
        }
        int excl = scw[t] - v;
        exs[t] = excl;
        cnt[t] = excl;          // fill cursor
        __syncthreads();
        for (int k = t; k < n; k += 256) {
            int d = ldc[k];
            int s = atomicAdd(&cnt[d], 1);
            idxl[s] = (unsigned short)k;
        }
        __syncthreads();
        for (int k = t; k < n; k += 256) {
            int kk = idxl[k];
            int d = ldc[kk];
            int pos = noff[d] + (k - exs[d]);
            epack[pos] = stage[beg + kk];   // gathered read (L2-hot), linear-run write
        }
    } else {
        for (int k = t; k < n; k += 256) {
            int d = sdst[beg + k] & 255;
            int r = atomicAdd(&cnt[d], 1);
            epack[noff[d] + r] = stage[beg + k];
        }
    }
}

// ================= layer 1: CSR gather (dim 7), 4-deep pipelined =================
__global__ void gather_d7(const float* __restrict__ x, const float4* __restrict__ epack,
                          const int* __restrict__ offsets,
                          const float* __restrict__ We, const float* __restrict__ be,
                          float* __restrict__ agg, int Nn)
{
    int tid = blockIdx.x * blockDim.x + threadIdx.x;
    int node = tid >> 3;
    int c = tid & 7;
    if (node >= Nn) return;
    float w0 = 0.f, w1 = 0.f, w2 = 0.f, b = 0.f;
    if (c < 7) { w0 = We[c]; w1 = We[7 + c]; w2 = We[14 + c]; b = be[c]; }
    int beg = offsets[node], end = offsets[node + 1];
    float acc = 0.f;
    int i = beg;
    for (; i + 4 <= end; i += 4) {
        float4 ep[4]; float xv[4];
#pragma unroll
        for (int j = 0; j < 4; ++j) ep[j] = epack[i + j];
#pragma unroll
        for (int j = 0; j < 4; ++j)
            xv[j] = (c < 7) ? x[__float_as_int(ep[j].x) * 7 + c] : 0.f;
#pragma unroll
        for (int j = 0; j < 4; ++j) {
            float v = b + xv[j];
            v = fmaf(ep[j].y, w0, v);
            v = fmaf(ep[j].z, w1, v);
            v = fmaf(ep[j].w, w2, v);
            acc += fmaxf(v, 0.f);
        }
    }
    int rem = end - i;
    if (rem > 0) {
        float4 ep[4]; float xv[4];
#pragma unroll
        for (int j = 0; j < 4; ++j) if (j < rem) ep[j] = epack[i + j];
#pragma unroll
        for (int j = 0; j < 4; ++j) if (j < rem)
            xv[j] = (c < 7) ? x[__float_as_int(ep[j].x) * 7 + c] : 0.f;
#pragma unroll
        for (int j = 0; j < 4; ++j) if (j < rem) {
            float v = b + xv[j];
            v = fmaf(ep[j].y, w0, v);
            v = fmaf(ep[j].z, w1, v);
            v = fmaf(ep[j].w, w2, v);
            acc += fmaxf(v, 0.f);
        }
    }
    if (c < 7) agg[node * 7 + c] = acc;
}

// ====== layers 2/3: gather with inline BN+ReLU, packed-pair math, NT aggp store ======
__global__ __launch_bounds__(256) void gather_d128(
    const unsigned short* __restrict__ h16,
    const float4* __restrict__ epack,
    const int* __restrict__ offsets,
    const float* __restrict__ We, const float* __restrict__ be,
    const float* __restrict__ sums, const float* __restrict__ g,
    const float* __restrict__ bt,
    unsigned* __restrict__ aggp, int Nn)
{
    __shared__ __align__(16) float as_[128], bs_[128];
    int t = threadIdx.x;
    if (t < 128) {
        float inv = 1.f / (float)Nn;
        float mu = sums[t] * inv;
        float var = sums[128 + t] * inv - mu * mu;
        float rs = rsqrtf(fmaxf(var, 0.f) + 1e-5f);
        float a = g[t] * rs;
        as_[t] = a;
        bs_[t] = bt[t] - a * mu;
    }
    __syncthreads();
    int node = blockIdx.x * 4 + (t >> 6);
    if (node >= Nn) return;
    int lane = t & 63;
    int beg = __builtin_amdgcn_readfirstlane(offsets[node]);
    int end = __builtin_amdgcn_readfirstlane(offsets[node + 1]);
    const f32x2* W2 = (const f32x2*)We;
    f32x2 w0 = W2[lane];
    f32x2 w1 = W2[64 + lane];
    f32x2 w2 = W2[128 + lane];
    f32x2 bb = ((const f32x2*)be)[lane];
    f32x2 aa = ((const f32x2*)as_)[lane];
    f32x2 ab = ((const f32x2*)bs_)[lane];
    const f32x2 zero2 = {0.f, 0.f};
    f32x2 acc2 = zero2;

    int i = beg;
    for (; i + 8 <= end; i += 8) {
        float4 e[8];
        unsigned p[8];
#pragma unroll
        for (int j = 0; j < 8; ++j) e[j] = epack[i + j];
#pragma unroll
        for (int j = 0; j < 8; ++j)
            p[j] = ((const unsigned*)(h16 + (size_t)__float_as_int(e[j].x) * HID))[lane];
#pragma unroll
        for (int j = 0; j < 8; ++j) {
            f32x2 hb = max2(fma2(bf2x2(p[j]), aa, ab), zero2);   // BN + relu (prev layer)
            f32x2 v = hb + bb;
            f32x2 ey = {e[j].y, e[j].y};
            f32x2 ez = {e[j].z, e[j].z};
            f32x2 ew = {e[j].w, e[j].w};
            v = fma2(ey, w0, v);
            v = fma2(ez, w1, v);
            v = fma2(ew, w2, v);
            acc2 += max2(v, zero2);                               // message relu + sum
        }
    }
    int rem = end - i;        // wave-uniform -> cheap s_cbranch predication
    if (rem > 0) {
        float4 e[8];
        unsigned p[8];
#pragma unroll
        for (int j = 0; j < 8; ++j) if (j < rem) e[j] = epack[i + j];
#pragma unroll
        for (int j = 0; j < 8; ++j) if (j < rem)
            p[j] = ((const unsigned*)(h16 + (size_t)__float_as_int(e[j].x) * HID))[lane];
#pragma unroll
        for (int j = 0; j < 8; ++j) if (j < rem) {
            f32x2 hb = max2(fma2(bf2x2(p[j]), aa, ab), zero2);
            f32x2 v = hb + bb;
            f32x2 ey = {e[j].y, e[j].y};
            f32x2 ez = {e[j].z, e[j].z};
            f32x2 ew = {e[j].w, e[j].w};
            v = fma2(ey, w0, v);
            v = fma2(ez, w1, v);
            v = fma2(ew, w2, v);
            acc2 += max2(v, zero2);
        }
    }
    // self term: BN+relu of own pre-BN row
    unsigned hv = ((const unsigned*)(h16 + (size_t)node * HID))[lane];
    f32x2 sf = max2(fma2(bf2x2(hv), aa, ab), zero2);
    u32x2 ov;
    ov.x = packhl(acc2.x + sf.x);
    ov.y = packhl(acc2.y + sf.y);
    // non-temporal: write-once stream; don't let 25MB of write-allocate evict
    // the hot h16 rows from L2 (consumer streams aggp linearly later)
    u32x2* dstp = (u32x2*)(aggp + (size_t)node * HID) + lane;
    __builtin_nontemporal_store(ov, dstp);
}

// ===== unpack interleaved hi/lo uint pairs into two bf16x8 via v_perm_b32 =====
__device__ __forceinline__ void unpack_hl(const unsigned* Tp, bf16x8& ah, bf16x8& al)
{
    uint4 pa = *(const uint4*)Tp;
    uint4 pb = *(const uint4*)(Tp + 4);
    union { unsigned u[4]; bf16x8 v; } H, L;
    H.u[0] = __builtin_amdgcn_perm(pa.y, pa.x, 0x05040100u);
    L.u[0] = __builtin_amdgcn_perm(pa.y, pa.x, 0x07060302u);
    H.u[1] = __builtin_amdgcn_perm(pa.w, pa.z, 0x05040100u);
    L.u[1] = __builtin_amdgcn_perm(pa.w, pa.z, 0x07060302u);
    H.u[2] = __builtin_amdgcn_perm(pb.y, pb.x, 0x05040100u);
    L.u[2] = __builtin_amdgcn_perm(pb.y, pb.x, 0x07060302u);
    H.u[3] = __builtin_amdgcn_perm(pb.w, pb.z, 0x05040100u);
    L.u[3] = __builtin_amdgcn_perm(pb.w, pb.z, 0x07060302u);
    ah = H.v;
    al = L.v;
}

// ===== MFMA core: acc[2][4] = T(64 rows packed hi/lo) @ Wt for this wave's 32 cols =====
__device__ __forceinline__ void mfma_core(
    const unsigned* T,
    const unsigned short* __restrict__ Wh, const unsigned short* __restrict__ Wl,
    const float* __restrict__ bias,
    int wave, int q, int li, f32x4 (&acc)[2][4])
{
    int ctg0 = wave * 2, ctg1 = wave * 2 + 1;
    float b0 = bias[ctg0 * 16 + li];
    float b1v = bias[ctg1 * 16 + li];
#pragma unroll
    for (int rf = 0; rf < 4; ++rf) {
        acc[0][rf][0] = b0;  acc[0][rf][1] = b0;  acc[0][rf][2] = b0;  acc[0][rf][3] = b0;
        acc[1][rf][0] = b1v; acc[1][rf][1] = b1v; acc[1][rf][2] = b1v; acc[1][rf][3] = b1v;
    }
#pragma unroll
    for (int kb = 0; kb < 4; ++kb) {
        int k0 = kb * 32 + q * 8;
        size_t w0off = (size_t)(ctg0 * 16 + li) * HID + k0;
        size_t w1off = (size_t)(ctg1 * 16 + li) * HID + k0;
        bf16x8 bh0 = *(const bf16x8*)(Wh + w0off);
        bf16x8 bl0 = *(const bf16x8*)(Wl + w0off);
        bf16x8 bh1 = *(const bf16x8*)(Wh + w1off);
        bf16x8 bl1 = *(const bf16x8*)(Wl + w1off);
#pragma unroll
        for (int rf = 0; rf < 4; ++rf) {
            const unsigned* Tp = T + (rf * 16 + li) * 132 + k0;
            bf16x8 ah, al;
            unpack_hl(Tp, ah, al);
            acc[0][rf] = __builtin_amdgcn_mfma_f32_16x16x32_bf16(ah, bh0, acc[0][rf], 0, 0, 0);
            acc[0][rf] = __builtin_amdgcn_mfma_f32_16x16x32_bf16(ah, bl0, acc[0][rf], 0, 0, 0);
            acc[0][rf] = __builtin_amdgcn_mfma_f32_16x16x32_bf16(al, bh0, acc[0][rf], 0, 0, 0);
            acc[1][rf] = __builtin_amdgcn_mfma_f32_16x16x32_bf16(ah, bh1, acc[1][rf], 0, 0, 0);
            acc[1][rf] = __builtin_amdgcn_mfma_f32_16x16x32_bf16(ah, bl1, acc[1][rf], 0, 0, 0);
            acc[1][rf] = __builtin_amdgcn_mfma_f32_16x16x32_bf16(al, bh1, acc[1][rf], 0, 0, 0);
        }
    }
}

// epilogue: h (pre-BN) -> bf16 via padded LDS bounce (conflict-free), stats to bnsums
__device__ __forceinline__ void epilogue_h16(
    f32x4 (&acc)[2][4], unsigned short* __restrict__ h16g,
    float* __restrict__ bnsums, float* sls, float* slq, unsigned short* Th,
    int node0, int wave, int q, int li, int t, int N)
{
#pragma unroll
    for (int ct = 0; ct < 2; ++ct) {
        int colb = (wave * 2 + ct) * 16 + li;
        float sv = 0.f, qv = 0.f;
#pragma unroll
        for (int rf = 0; rf < 4; ++rf) {
#pragma unroll
            for (int r = 0; r < 4; ++r) {
                int rloc = rf * 16 + q * 4 + r;
                float v = acc[ct][rf][r];
                Th[rloc * TH_STRIDE + colb] = f2bf(v);
                if (node0 + rloc < N) { sv += v; qv = fmaf(v, v, qv); }
            }
        }
        sv += __shfl_down(sv, 16); sv += __shfl_down(sv, 32);
        qv += __shfl_down(qv, 16); qv += __shfl_down(qv, 32);
        if (q == 0) { sls[colb] = sv; slq[colb] = qv; }
    }
    __syncthreads();
    int rows = N - node0; if (rows > 64) rows = 64;
    uint2* dstp = (uint2*)(h16g + (size_t)node0 * HID);
    const uint2* srcp = (const uint2*)Th;        // row stride 33 uint2 (132 shorts)
    for (int i = t; i < rows * 32; i += 256) {
        int row = i >> 5, c = i & 31;
        dstp[i] = srcp[row * 33 + c];
    }
    if (t < 128) {
        atomicAdd(&bnsums[t], sls[t]);
        atomicAdd(&bnsums[128 + t], slq[t]);
    }
}

// ===== fused MLP layers 2/3: h16 = bf16(Lin2(relu(Lin1(A)))), stats fused =====
__global__ __launch_bounds__(256) void mlp128_fused(
    const unsigned* __restrict__ Ap,
    const unsigned short* __restrict__ W1h, const unsigned short* __restrict__ W1l,
    const float* __restrict__ b1,
    const unsigned short* __restrict__ W2h, const unsigned short* __restrict__ W2l,
    const float* __restrict__ b2,
    unsigned short* __restrict__ h16g, float* __restrict__ bnsums, int N)
{
    __shared__ unsigned Ta[64 * 132];
    __shared__ unsigned Tb[64 * 132];
    __shared__ float sls[128], slq[128];
    int t = threadIdx.x;
    int wave = t >> 6, lane = t & 63;
    int q = lane >> 4, li = lane & 15;
    int node0 = blockIdx.x * 64;

    // ---- stage A (already packed): straight uint4 copy global -> padded LDS ----
    {
        const uint4* A4 = (const uint4*)(Ap + (size_t)node0 * HID);
        int rows = N - node0 < 64 ? (N - node0) : 64;
        int limit4 = 32 * rows;
#pragma unroll
        for (int i = 0; i < 8; ++i) {
            int idx = t + i * 256;
            uint4 v = {0u, 0u, 0u, 0u};
            if (idx < limit4) v = A4[idx];
            int row = idx >> 5, c4 = idx & 31;
            *(uint4*)(Ta + row * 132 + c4 * 4) = v;
        }
    }
    __syncthreads();

    // ---- phase 1: Ta @ W1 -> relu -> packed Tb ----
    {
        f32x4 acc[2][4];
        mfma_core(Ta, W1h, W1l, b1, wave, q, li, acc);
#pragma unroll
        for (int ct = 0; ct < 2; ++ct) {
            int colb = (wave * 2 + ct) * 16 + li;
#pragma unroll
            for (int rf = 0; rf < 4; ++rf) {
#pragma unroll
                for (int r = 0; r < 4; ++r) {
                    float v = fmaxf(acc[ct][rf][r], 0.f);
                    Tb[(rf * 16 + q * 4 + r) * 132 + colb] = packhl(v);
                }
            }
        }
    }
    __syncthreads();

    // ---- phase 2: Tb @ W2 -> h16 (+stats); dead Ta reused as bf16 bounce buffer ----
    {
        f32x4 acc[2][4];
        mfma_core(Tb, W2h, W2l, b2, wave, q, li, acc);
        epilogue_h16(acc, h16g, bnsums, sls, slq, (unsigned short*)Ta,
                     node0, wave, q, li, t, N);
    }
}

// ===== fused MLP layer 1: phase-1 K=7 fp32 vector (x+agg7) -> packed Tb, phase-2 MFMA =====
__global__ __launch_bounds__(256) void mlp1_fused(
    const float* __restrict__ x, const float* __restrict__ agg,
    const float* __restrict__ W1, const float* __restrict__ b1,     // [7][128]
    const unsigned short* __restrict__ W2h, const unsigned short* __restrict__ W2l,
    const float* __restrict__ b2,
    unsigned short* __restrict__ h16g, float* __restrict__ bnsums, int N)
{
    __shared__ unsigned Tb[64 * 132];
    __shared__ unsigned short Th[64 * TH_STRIDE];
    __shared__ float sls[128], slq[128];
    int t = threadIdx.x;
    int wave = t >> 6, lane = t & 63;
    int q = lane >> 4, li = lane & 15;
    int node0 = blockIdx.x * 64;

    // phase 1: rows wave*16+li (4 waves cover 64 rows), q covers col-groups of 32
    {
        int row = node0 + wave * 16 + li;
        bool ok = row < N;
        float xa[7];
#pragma unroll
        for (int k = 0; k < 7; ++k) xa[k] = ok ? (x[row * 7 + k] + agg[row * 7 + k]) : 0.f;
        const float4* W14 = (const float4*)W1;
        const float4* b14 = (const float4*)b1;
        unsigned* Trow = Tb + (wave * 16 + li) * 132 + q * 32;
#pragma unroll
        for (int c4 = 0; c4 < 8; ++c4) {
            float4 v = b14[q * 8 + c4];
#pragma unroll
            for (int k = 0; k < 7; ++k) {
                float4 w = W14[k * 32 + q * 8 + c4];
                v.x = fmaf(xa[k], w.x, v.x);
                v.y = fmaf(xa[k], w.y, v.y);
                v.z = fmaf(xa[k], w.z, v.z);
                v.w = fmaf(xa[k], w.w, v.w);
            }
            uint4 pk;
            pk.x = packhl(fmaxf(v.x, 0.f));
            pk.y = packhl(fmaxf(v.y, 0.f));
            pk.z = packhl(fmaxf(v.z, 0.f));
            pk.w = packhl(fmaxf(v.w, 0.f));
            *(uint4*)(Trow + c4 * 4) = pk;
        }
    }
    __syncthreads();

    // phase 2
    {
        f32x4 acc[2][4];
        mfma_core(Tb, W2h, W2l, b2, wave, q, li, acc);
        epilogue_h16(acc, h16g, bnsums, sls, slq, Th, node0, wave, q, li, t, N);
    }
}

// ===== layer-3 BN-apply + mean-pool from bf16 h16 (batch sorted, segmented) =====
__global__ __launch_bounds__(256) void bn_pool(
    const unsigned short* __restrict__ h16, const float* __restrict__ sums,
    const float* __restrict__ g, const float* __restrict__ bt,
    const int* __restrict__ batch,
    float* __restrict__ pools, float* __restrict__ cnt, int Nn)
{
    __shared__ float as_[128], bs_[128];
    int t = threadIdx.x;
    if (t < 128) {
        float inv = 1.f / (float)Nn;
        float mu = sums[t] * inv;
        float var = sums[128 + t] * inv - mu * mu;
        float rs = rsqrtf(fmaxf(var, 0.f) + 1e-5f);
        float a = g[t] * rs;
        as_[t] = a;
        bs_[t] = bt[t] - a * mu;
    }
    __syncthreads();
    int half = t >> 7;
    int c = t & 127;
    int base = blockIdx.x * 64 + half * 32;
    if (base >= Nn) return;
    int lim = base + 32 < Nn ? base + 32 : Nn;
    int g0 = batch[base];
    float s = 0.f, ncnt = 0.f;
    for (int n = base; n < lim; ++n) {
        int gg = batch[n];
        if (gg != g0) {
            atomicAdd(&pools[(size_t)g0 * HID + c], s);
            if (c == 0) atomicAdd(&cnt[g0], ncnt);
            s = 0.f; ncnt = 0.f; g0 = gg;
        }
        float hraw = bf2f(h16[(size_t)n * HID + c]);
        float v = fmaxf(fmaf(hraw, as_[c], bs_[c]), 0.f);
        s += v;
        ncnt += 1.f;
    }
    atomicAdd(&pools[(size_t)g0 * HID + c], s);
    if (c == 0) atomicAdd(&cnt[g0], ncnt);
}

__global__ void head_kernel(const float* __restrict__ pools, const float* __restrict__ cnt,
                            const float* __restrict__ Wf1, const float* __restrict__ bf1,
                            const float* __restrict__ Wf2, const float* __restrict__ bf2,
                            float* __restrict__ out, int G)
{
    int g = blockIdx.x;
    int t = threadIdx.x;
    __shared__ float p[128];
    float inv = 1.f / fmaxf(cnt[g], 1.f);
    p[t] = pools[g * 128 + t] * inv;
    p[t + 64] = pools[g * 128 + t + 64] * inv;
    __syncthreads();
    float o = bf1[t];
#pragma unroll 8
    for (int k = 0; k < 128; ++k) o = fmaf(p[k], Wf1[k * 64 + t], o);
    o = fmaxf(o, 0.f);
    float prod = o * Wf2[t];
#pragma unroll
    for (int off = 32; off > 0; off >>= 1) prod += __shfl_down(prod, off);
    if (t == 0) out[g] = prod + bf2[0];
}

extern "C" void kernel_launch(void* const* d_in, const int* in_sizes, int n_in,
                              void* d_out, int out_size, void* d_ws, size_t ws_size,
                              hipStream_t stream)
{
    const float* x     = (const float*)d_in[0];
    const float* ea    = (const float*)d_in[1];
    const int*   eidx  = (const int*)d_in[2];
    const int*   batch = (const int*)d_in[3];
    const float* We1 = (const float*)d_in[4];  const float* be1 = (const float*)d_in[5];
    const float* W11 = (const float*)d_in[6];  const float* b11 = (const float*)d_in[7];
    const float* W12 = (const float*)d_in[8];  const float* b12 = (const float*)d_in[9];
    const float* g1  = (const float*)d_in[10]; const float* bt1 = (const float*)d_in[11];
    const float* We2 = (const float*)d_in[12]; const float* be2 = (const float*)d_in[13];
    const float* W21 = (const float*)d_in[14]; const float* b21 = (const float*)d_in[15];
    const float* W22 = (const float*)d_in[16]; const float* b22 = (const float*)d_in[17];
    const float* g2  = (const float*)d_in[18]; const float* bt2 = (const float*)d_in[19];
    const float* We3 = (const float*)d_in[20]; const float* be3 = (const float*)d_in[21];
    const float* W31 = (const float*)d_in[22]; const float* b31 = (const float*)d_in[23];
    const float* W32 = (const float*)d_in[24]; const float* b32 = (const float*)d_in[25];
    const float* g3  = (const float*)d_in[26]; const float* bt3 = (const float*)d_in[27];
    const float* Wf1 = (const float*)d_in[28]; const float* bf1 = (const float*)d_in[29];
    const float* Wf2 = (const float*)d_in[30]; const float* bf2 = (const float*)d_in[31];

    const int N = in_sizes[0] / 7;
    const int E = in_sizes[1] / 3;
    const int G = out_size;
    const int* src = eidx;
    const int* dst = eidx + E;

    float* ws = (float*)d_ws;
    float4* stage    = (float4*)ws;                          // E float4 (sort staging)
    int*    sdst     = (int*)(stage + E);                    // E ints
    unsigned* aggp   = (unsigned*)(sdst + E);                // N*128 packed hi/lo agg
    float* agg7      = (float*)(aggp + (size_t)N * HID);     // N*7
    float* bnsums    = agg7 + (size_t)N * 7;                 // 3 x 256
    float* pools     = bnsums + 768;                         // G*128
    float* cntp      = pools + (size_t)G * HID;              // G
    size_t fused     = (size_t)(cntp + G - ws);
    fused = (fused + 3) & ~(size_t)3;                        // 16B align for epack
    float4* epack    = (float4*)(ws + fused);                // E float4
    unsigned short* h16 = (unsigned short*)(epack + E);      // N*128 bf16 (pre-BN h)
    int*   icnt      = (int*)(h16 + (size_t)N * HID);        // N
    int*   ioffs     = icnt + N;                             // N+1
    int*   ibcur     = ioffs + N + 1;                        // 256 (bucket slice cursors)
    int*   ipart     = ibcur + 256;                          // 256
    int*   iexcl     = ipart + 256;                          // N
    unsigned short* wt = (unsigned short*)(iexcl + N);       // 5 x 2 x 16384
    unsigned short* w12h = wt;            unsigned short* w12l = wt + 16384;
    unsigned short* w21h = wt + 32768;    unsigned short* w21l = wt + 49152;
    unsigned short* w22h = wt + 65536;    unsigned short* w22l = wt + 81920;
    unsigned short* w31h = wt + 98304;    unsigned short* w31l = wt + 114688;
    unsigned short* w32h = wt + 131072;   unsigned short* w32l = wt + 147456;

    const unsigned grid_mfma = (unsigned)((N + 63) / 64);
    const unsigned nb_scan   = (unsigned)((N + 255) / 256);
    const unsigned grid_gather = (unsigned)((N + 3) / 4);
    const unsigned grid_gat7 = (unsigned)(((long long)N * 8 + 255) / 256);
    const unsigned grid_pool = (unsigned)((N + 63) / 64);
    const unsigned grid_part = (unsigned)((E + CHUNK - 1) / CHUNK);
    const unsigned grid_buck = (unsigned)((N + 255) / 256);
    const long long PZ = (long long)G * HID + G;

    // ---------- preamble: W splits + zeros + histogram (one launch) ----------
    hipMemsetAsync(icnt, 0, (size_t)N * sizeof(int), stream);
    fused_pre<<<1122, 256, 0, stream>>>(W12, W21, W22, W31, W32, wt,
                                        bnsums, pools, PZ, dst, icnt, E);

    // ---------- CSR offsets + two-phase edge sort ----------
    scan_block<<<nb_scan, 256, 0, stream>>>(icnt, iexcl, ipart, N);
    scan_addf<<<nb_scan, 256, 0, stream>>>(iexcl, ipart, (int)nb_scan, ioffs, ibcur, N, E);
    epart<<<grid_part, 256, 0, stream>>>(dst, src, ea, ibcur, stage, sdst, E);
    elocal<<<grid_buck, 256, 0, stream>>>(stage, sdst, ioffs, epack, N);

    // ---------- layer 1 ----------
    gather_d7<<<grid_gat7, 256, 0, stream>>>(x, epack, ioffs, We1, be1, agg7, N);
    mlp1_fused<<<grid_mfma, 256, 0, stream>>>(x, agg7, W11, b11, w12h, w12l, b12,
                                              h16, bnsums, N);

    // ---------- layer 2 ----------
    gather_d128<<<grid_gather, 256, 0, stream>>>(h16, epack, ioffs, We2, be2,
                                                 bnsums, g1, bt1, aggp, N);
    mlp128_fused<<<grid_mfma, 256, 0, stream>>>(aggp, w21h, w21l, b21, w22h, w22l, b22,
                                                h16, bnsums + 256, N);

    // ---------- layer 3 ----------
    gather_d128<<<grid_gather, 256, 0, stream>>>(h16, epack, ioffs, We3, be3,
                                                 bnsums + 256, g2, bt2, aggp, N);
    mlp128_fused<<<grid_mfma, 256, 0, stream>>>(aggp, w31h, w31l, b31, w32h, w32l, b32,
                                                h16, bnsums + 512, N);

    // ---------- BN-apply + segmented pool + head ----------
    bn_pool<<<grid_pool, 256, 0, stream>>>(h16, bnsums + 512, g3, bt3, batch,
                                           pools, cntp, N);
    head_kernel<<<G, 64, 0, stream>>>(pools, cntp, Wf1, bf1, Wf2, bf2, (float*)d_out, G);
}

// Round 11
// 431.679 us; speedup vs baseline: 1.1708x; 1.0144x over previous
//
#include <hip/hip_runtime.h>

#define HID 128
#define CHUNK 3072      // edges per epart block
#define CAP2 5120       // max edges per 256-node bucket in elocal fast path
#define TH_STRIDE 132   // padded bf16 bounce-row stride (shorts): conflict-free epilogue

typedef __attribute__((ext_vector_type(8))) short bf16x8;
typedef __attribute__((ext_vector_type(4))) float f32x4;
typedef __attribute__((ext_vector_type(2))) float f32x2;
typedef __attribute__((ext_vector_type(2))) unsigned u32x2;

__device__ inline unsigned short f2bf(float f) {
    unsigned u = __float_as_uint(f);
    unsigned r = (u + 0x7fff + ((u >> 16) & 1)) >> 16;
    return (unsigned short)r;
}
__device__ inline float bf2f(unsigned short b) {
    return __uint_as_float(((unsigned)b) << 16);
}
// split v into trunc-bf16 hi (low 16 bits) + trunc-bf16 lo (high 16 bits)
__device__ inline unsigned packhl(float v) {
    unsigned h = __float_as_uint(v) >> 16;
    float lo = v - __uint_as_float(h << 16);
    unsigned l = __float_as_uint(lo) >> 16;
    return h | (l << 16);
}

// packed-pair helpers: map to v_pk_fma_f32 / v_pk_max_f32 on gfx950
__device__ __forceinline__ f32x2 fma2(f32x2 a, f32x2 b, f32x2 c) {
    return __builtin_elementwise_fma(a, b, c);
}
__device__ __forceinline__ f32x2 max2(f32x2 a, f32x2 b) {
    return __builtin_elementwise_max(a, b);
}
// two bf16 cols packed in one uint -> f32 pair (lo short = col x, hi short = col y)
__device__ __forceinline__ f32x2 bf2x2(unsigned pv) {
    f32x2 r;
    r.x = __uint_as_float(pv << 16);
    r.y = __uint_as_float(pv & 0xffff0000u);
    return r;
}

// ===== fused preamble: W hi/lo splits + bnsums/pools zero + dst histogram =====
__global__ __launch_bounds__(256) void fused_pre(
    const float* __restrict__ W12, const float* __restrict__ W21,
    const float* __restrict__ W22, const float* __restrict__ W31,
    const float* __restrict__ W32, unsigned short* __restrict__ wt,
    float* __restrict__ bnsums, float* __restrict__ poolz, long long PZ,
    const int* __restrict__ dst, int* __restrict__ icnt, int E)
{
    int b = blockIdx.x, t = threadIdx.x;
    if (b < 320) {
        int w = b >> 6;
        int idx = (b & 63) * 256 + t;
        const float* W = (w == 0) ? W12 : (w == 1) ? W21 : (w == 2) ? W22 : (w == 3) ? W31 : W32;
        unsigned short* wh = wt + (size_t)w * 32768;
        unsigned short* wl = wh + 16384;
        int n = idx >> 7, k = idx & 127;
        float wv = W[k * 128 + n];
        unsigned short h = (unsigned short)(__float_as_uint(wv) >> 16);
        float lo = wv - bf2f(h);
        unsigned short l = (unsigned short)(__float_as_uint(lo) >> 16);
        wh[idx] = h;
        wl[idx] = l;
    } else if (b == 320) {
        for (int i = t; i < 768; i += 256) bnsums[i] = 0.f;
    } else if (b < 338) {
        long long s0 = (long long)(b - 321) * 16384;
        long long e1 = s0 + 16384; if (e1 > PZ) e1 = PZ;
        for (long long i = s0 + t; i < e1; i += 256) poolz[i] = 0.f;
    } else {
        int stride = (gridDim.x - 338) * 256;
        for (int e = (b - 338) * 256 + t; e < E; e += stride)
            atomicAdd(&icnt[dst[e]], 1);
    }
}

// ================= CSR scan =================
__global__ void scan_block(const int* __restrict__ cnt, int* __restrict__ excl,
                           int* __restrict__ partials, int Nn)
{
    __shared__ int ls[256];
    int i = blockIdx.x * 256 + threadIdx.x;
    int v = (i < Nn) ? cnt[i] : 0;
    ls[threadIdx.x] = v;
    __syncthreads();
    for (int off = 1; off < 256; off <<= 1) {
        int t = (threadIdx.x >= off) ? ls[threadIdx.x - off] : 0;
        __syncthreads();
        ls[threadIdx.x] += t;
        __syncthreads();
    }
    if (i < Nn) excl[i] = ls[threadIdx.x] - v;
    if (threadIdx.x == 255) partials[blockIdx.x] = ls[255];
}

// per-block redundant partials scan + offsets/bcur write (replaces 2 kernels)
__global__ void scan_addf(const int* __restrict__ excl, const int* __restrict__ partials,
                          int nb, int* __restrict__ offsets, int* __restrict__ bcur,
                          int Nn, int E)
{
    __shared__ int ls[256];
    int t = threadIdx.x;
    int v = (t < nb) ? partials[t] : 0;
    ls[t] = v;
    __syncthreads();
    for (int off = 1; off < 256; off <<= 1) {
        int x = (t >= off) ? ls[t - off] : 0;
        __syncthreads();
        ls[t] += x;
        __syncthreads();
    }
    int base = (blockIdx.x > 0) ? ls[blockIdx.x - 1] : 0;
    int i = blockIdx.x * 256 + t;
    if (i < Nn) {
        int o = excl[i] + base;
        offsets[i] = o;
        if ((i & 255) == 0) bcur[i >> 8] = o;
    }
    if (blockIdx.x == 0 && t == 0) offsets[Nn] = E;
}

// ===== epart: partition edges into 256-node MSD buckets (index-staged, LDS-light) =====
__global__ __launch_bounds__(256) void epart(
    const int* __restrict__ dst, const int* __restrict__ src,
    const float* __restrict__ ea, int* __restrict__ bcur,
    float4* __restrict__ stage, int* __restrict__ sdst, int E)
{
    __shared__ int dl[CHUNK];              // 12KB: dst value per original k
    __shared__ unsigned short idxl[CHUNK]; // 6KB: original k per sorted slot
    __shared__ int cnt[256], gsl[256], exs[256], scw[256];
    int t = threadIdx.x;
    int e0 = blockIdx.x * CHUNK;
    int n = E - e0; if (n > CHUNK) n = CHUNK;
    cnt[t] = 0;
    __syncthreads();
    for (int k = t; k < n; k += 256) {
        int dv = dst[e0 + k];
        dl[k] = dv;
        atomicAdd(&cnt[dv >> 8], 1);
    }
    __syncthreads();
    int v = cnt[t];
    int gb = 0;
    if (v > 0) gb = atomicAdd(&bcur[t], v);
    gsl[t] = gb;
    scw[t] = v;
    __syncthreads();
    for (int off = 1; off < 256; off <<= 1) {
        int x = (t >= off) ? scw[t - off] : 0;
        __syncthreads();
        scw[t] += x;
        __syncthreads();
    }
    int excl = scw[t] - v;
    exs[t] = excl;
    cnt[t] = excl;              // fill cursor
    __syncthreads();
    for (int k = t; k < n; k += 256) {
        int d = dl[k] >> 8;
        int s = atomicAdd(&cnt[d], 1);
        idxl[s] = (unsigned short)k;
    }
    __syncthreads();
    // writeout: consecutive slots -> consecutive stage addresses per bucket run
    for (int k = t; k < n; k += 256) {
        int kk = idxl[k];
        int dv = dl[kk];
        int d = dv >> 8;
        int pos = gsl[d] + (k - exs[d]);
        int e = e0 + kk;
        float4 p;
        p.x = __int_as_float(src[e]);
        p.y = ea[e * 3];
        p.z = ea[e * 3 + 1];
        p.w = ea[e * 3 + 2];
        stage[pos] = p;
        sdst[pos] = dv;
    }
}

// ===== elocal: per-bucket counting sort into final CSR epack (index-staged) =====
__global__ __launch_bounds__(256) void elocal(
    const float4* __restrict__ stage, const int* __restrict__ sdst,
    const int* __restrict__ offsets, float4* __restrict__ epack, int Nn)
{
    __shared__ unsigned short idxl[CAP2];  // 10KB
    __shared__ unsigned char  ldc[CAP2];   // 5KB: local dst (0..255)
    __shared__ int cnt[256], exs[256], noff[256], scw[256];
    int t = threadIdx.x;
    int b = blockIdx.x;
    int nbeg = b << 8;
    int nend = nbeg + 256; if (nend > Nn) nend = Nn;
    int beg = offsets[nbeg];
    int end = offsets[nend];
    int n = end - beg;
    noff[t] = (nbeg + t < Nn) ? offsets[nbeg + t] : 0;
    cnt[t] = 0;
    __syncthreads();
    if (n <= CAP2) {
        for (int k = t; k < n; k += 256) {
            int d = sdst[beg + k] & 255;
            ldc[k] = (unsigned char)d;
            atomicAdd(&cnt[d], 1);
        }
        __syncthreads();
        int v = cnt[t];
        scw[t] = v;
        __syncthreads();
        for (int off = 1; off < 256; off <<= 1) {
            int x = (t >= off) ? scw[t - off] : 0;
            __syncthreads();
            scw[t] += x;
            __syncthreads();
        }
        int excl = scw[t] - v;
        exs[t] = excl;
        cnt[t] = excl;          // fill cursor
        __syncthreads();
        for (int k = t; k < n; k += 256) {
            int d = ldc[k];
            int s = atomicAdd(&cnt[d], 1);
            idxl[s] = (unsigned short)k;
        }
        __syncthreads();
        for (int k = t; k < n; k += 256) {
            int kk = idxl[k];
            int d = ldc[kk];
            int pos = noff[d] + (k - exs[d]);
            epack[pos] = stage[beg + kk];   // gathered read (L2-hot), linear-run write
        }
    } else {
        for (int k = t; k < n; k += 256) {
            int d = sdst[beg + k] & 255;
            int r = atomicAdd(&cnt[d], 1);
            epack[noff[d] + r] = stage[beg + k];
        }
    }
}

// ================= layer 1: CSR gather (dim 7), 4-deep pipelined =================
__global__ void gather_d7(const float* __restrict__ x, const float4* __restrict__ epack,
                          const int* __restrict__ offsets,
                          const float* __restrict__ We, const float* __restrict__ be,
                          float* __restrict__ agg, int Nn)
{
    int tid = blockIdx.x * blockDim.x + threadIdx.x;
    int node = tid >> 3;
    int c = tid & 7;
    if (node >= Nn) return;
    float w0 = 0.f, w1 = 0.f, w2 = 0.f, b = 0.f;
    if (c < 7) { w0 = We[c]; w1 = We[7 + c]; w2 = We[14 + c]; b = be[c]; }
    int beg = offsets[node], end = offsets[node + 1];
    float acc = 0.f;
    int i = beg;
    for (; i + 4 <= end; i += 4) {
        float4 ep[4]; float xv[4];
#pragma unroll
        for (int j = 0; j < 4; ++j) ep[j] = epack[i + j];
#pragma unroll
        for (int j = 0; j < 4; ++j)
            xv[j] = (c < 7) ? x[__float_as_int(ep[j].x) * 7 + c] : 0.f;
#pragma unroll
        for (int j = 0; j < 4; ++j) {
            float v = b + xv[j];
            v = fmaf(ep[j].y, w0, v);
            v = fmaf(ep[j].z, w1, v);
            v = fmaf(ep[j].w, w2, v);
            acc += fmaxf(v, 0.f);
        }
    }
    int rem = end - i;
    if (rem > 0) {
        float4 ep[4]; float xv[4];
#pragma unroll
        for (int j = 0; j < 4; ++j) if (j < rem) ep[j] = epack[i + j];
#pragma unroll
        for (int j = 0; j < 4; ++j) if (j < rem)
            xv[j] = (c < 7) ? x[__float_as_int(ep[j].x) * 7 + c] : 0.f;
#pragma unroll
        for (int j = 0; j < 4; ++j) if (j < rem) {
            float v = b + xv[j];
            v = fmaf(ep[j].y, w0, v);
            v = fmaf(ep[j].z, w1, v);
            v = fmaf(ep[j].w, w2, v);
            acc += fmaxf(v, 0.f);
        }
    }
    if (c < 7) agg[node * 7 + c] = acc;
}

// ====== layers 2/3: gather with inline BN+ReLU, packed-pair math, NT aggp store ======
__global__ __launch_bounds__(256) void gather_d128(
    const unsigned short* __restrict__ h16,
    const float4* __restrict__ epack,
    const int* __restrict__ offsets,
    const float* __restrict__ We, const float* __restrict__ be,
    const float* __restrict__ sums, const float* __restrict__ g,
    const float* __restrict__ bt,
    unsigned* __restrict__ aggp, int Nn)
{
    __shared__ __align__(16) float as_[128], bs_[128];
    int t = threadIdx.x;
    if (t < 128) {
        float inv = 1.f / (float)Nn;
        float mu = sums[t] * inv;
        float var = sums[128 + t] * inv - mu * mu;
        float rs = rsqrtf(fmaxf(var, 0.f) + 1e-5f);
        float a = g[t] * rs;
        as_[t] = a;
        bs_[t] = bt[t] - a * mu;
    }
    __syncthreads();
    int node = blockIdx.x * 4 + (t >> 6);
    if (node >= Nn) return;
    int lane = t & 63;
    int beg = __builtin_amdgcn_readfirstlane(offsets[node]);
    int end = __builtin_amdgcn_readfirstlane(offsets[node + 1]);
    const f32x2* W2 = (const f32x2*)We;
    f32x2 w0 = W2[lane];
    f32x2 w1 = W2[64 + lane];
    f32x2 w2 = W2[128 + lane];
    f32x2 bb = ((const f32x2*)be)[lane];
    f32x2 aa = ((const f32x2*)as_)[lane];
    f32x2 ab = ((const f32x2*)bs_)[lane];
    const f32x2 zero2 = {0.f, 0.f};
    f32x2 acc2 = zero2;

    int i = beg;
    for (; i + 8 <= end; i += 8) {
        float4 e[8];
        unsigned p[8];
#pragma unroll
        for (int j = 0; j < 8; ++j) e[j] = epack[i + j];
#pragma unroll
        for (int j = 0; j < 8; ++j)
            p[j] = ((const unsigned*)(h16 + (size_t)__float_as_int(e[j].x) * HID))[lane];
#pragma unroll
        for (int j = 0; j < 8; ++j) {
            f32x2 hb = max2(fma2(bf2x2(p[j]), aa, ab), zero2);   // BN + relu (prev layer)
            f32x2 v = hb + bb;
            f32x2 ey = {e[j].y, e[j].y};
            f32x2 ez = {e[j].z, e[j].z};
            f32x2 ew = {e[j].w, e[j].w};
            v = fma2(ey, w0, v);
            v = fma2(ez, w1, v);
            v = fma2(ew, w2, v);
            acc2 += max2(v, zero2);                               // message relu + sum
        }
    }
    int rem = end - i;        // wave-uniform -> cheap s_cbranch predication
    if (rem > 0) {
        float4 e[8];
        unsigned p[8];
#pragma unroll
        for (int j = 0; j < 8; ++j) if (j < rem) e[j] = epack[i + j];
#pragma unroll
        for (int j = 0; j < 8; ++j) if (j < rem)
            p[j] = ((const unsigned*)(h16 + (size_t)__float_as_int(e[j].x) * HID))[lane];
#pragma unroll
        for (int j = 0; j < 8; ++j) if (j < rem) {
            f32x2 hb = max2(fma2(bf2x2(p[j]), aa, ab), zero2);
            f32x2 v = hb + bb;
            f32x2 ey = {e[j].y, e[j].y};
            f32x2 ez = {e[j].z, e[j].z};
            f32x2 ew = {e[j].w, e[j].w};
            v = fma2(ey, w0, v);
            v = fma2(ez, w1, v);
            v = fma2(ew, w2, v);
            acc2 += max2(v, zero2);
        }
    }
    // self term: BN+relu of own pre-BN row
    unsigned hv = ((const unsigned*)(h16 + (size_t)node * HID))[lane];
    f32x2 sf = max2(fma2(bf2x2(hv), aa, ab), zero2);
    u32x2 ov;
    ov.x = packhl(acc2.x + sf.x);
    ov.y = packhl(acc2.y + sf.y);
    // non-temporal: write-once stream; don't evict hot h16 rows from L2
    u32x2* dstp = (u32x2*)(aggp + (size_t)node * HID) + lane;
    __builtin_nontemporal_store(ov, dstp);
}

// ===== unpack interleaved hi/lo uint pairs into two bf16x8 via v_perm_b32 =====
__device__ __forceinline__ void unpack_hl(const unsigned* Tp, bf16x8& ah, bf16x8& al)
{
    uint4 pa = *(const uint4*)Tp;
    uint4 pb = *(const uint4*)(Tp + 4);
    union { unsigned u[4]; bf16x8 v; } H, L;
    H.u[0] = __builtin_amdgcn_perm(pa.y, pa.x, 0x05040100u);
    L.u[0] = __builtin_amdgcn_perm(pa.y, pa.x, 0x07060302u);
    H.u[1] = __builtin_amdgcn_perm(pa.w, pa.z, 0x05040100u);
    L.u[1] = __builtin_amdgcn_perm(pa.w, pa.z, 0x07060302u);
    H.u[2] = __builtin_amdgcn_perm(pb.y, pb.x, 0x05040100u);
    L.u[2] = __builtin_amdgcn_perm(pb.y, pb.x, 0x07060302u);
    H.u[3] = __builtin_amdgcn_perm(pb.w, pb.z, 0x05040100u);
    L.u[3] = __builtin_amdgcn_perm(pb.w, pb.z, 0x07060302u);
    ah = H.v;
    al = L.v;
}

// ===== MFMA core: acc[2][4] = T(64 rows packed hi/lo) @ Wt for this wave's 32 cols =====
__device__ __forceinline__ void mfma_core(
    const unsigned* T,
    const unsigned short* __restrict__ Wh, const unsigned short* __restrict__ Wl,
    const float* __restrict__ bias,
    int wave, int q, int li, f32x4 (&acc)[2][4])
{
    int ctg0 = wave * 2, ctg1 = wave * 2 + 1;
    float b0 = bias[ctg0 * 16 + li];
    float b1v = bias[ctg1 * 16 + li];
#pragma unroll
    for (int rf = 0; rf < 4; ++rf) {
        acc[0][rf][0] = b0;  acc[0][rf][1] = b0;  acc[0][rf][2] = b0;  acc[0][rf][3] = b0;
        acc[1][rf][0] = b1v; acc[1][rf][1] = b1v; acc[1][rf][2] = b1v; acc[1][rf][3] = b1v;
    }
#pragma unroll
    for (int kb = 0; kb < 4; ++kb) {
        int k0 = kb * 32 + q * 8;
        size_t w0off = (size_t)(ctg0 * 16 + li) * HID + k0;
        size_t w1off = (size_t)(ctg1 * 16 + li) * HID + k0;
        bf16x8 bh0 = *(const bf16x8*)(Wh + w0off);
        bf16x8 bl0 = *(const bf16x8*)(Wl + w0off);
        bf16x8 bh1 = *(const bf16x8*)(Wh + w1off);
        bf16x8 bl1 = *(const bf16x8*)(Wl + w1off);
#pragma unroll
        for (int rf = 0; rf < 4; ++rf) {
            const unsigned* Tp = T + (rf * 16 + li) * 132 + k0;
            bf16x8 ah, al;
            unpack_hl(Tp, ah, al);
            acc[0][rf] = __builtin_amdgcn_mfma_f32_16x16x32_bf16(ah, bh0, acc[0][rf], 0, 0, 0);
            acc[0][rf] = __builtin_amdgcn_mfma_f32_16x16x32_bf16(ah, bl0, acc[0][rf], 0, 0, 0);
            acc[0][rf] = __builtin_amdgcn_mfma_f32_16x16x32_bf16(al, bh0, acc[0][rf], 0, 0, 0);
            acc[1][rf] = __builtin_amdgcn_mfma_f32_16x16x32_bf16(ah, bh1, acc[1][rf], 0, 0, 0);
            acc[1][rf] = __builtin_amdgcn_mfma_f32_16x16x32_bf16(ah, bl1, acc[1][rf], 0, 0, 0);
            acc[1][rf] = __builtin_amdgcn_mfma_f32_16x16x32_bf16(al, bh1, acc[1][rf], 0, 0, 0);
        }
    }
}

// epilogue: h (pre-BN) -> bf16 via padded LDS bounce (conflict-free), stats to bnsums
// NOTE: caller must __syncthreads() before calling if Th aliases the MFMA input buffer
__device__ __forceinline__ void epilogue_h16(
    f32x4 (&acc)[2][4], unsigned short* __restrict__ h16g,
    float* __restrict__ bnsums, float* sls, float* slq, unsigned short* Th,
    int node0, int wave, int q, int li, int t, int N)
{
#pragma unroll
    for (int ct = 0; ct < 2; ++ct) {
        int colb = (wave * 2 + ct) * 16 + li;
        float sv = 0.f, qv = 0.f;
#pragma unroll
        for (int rf = 0; rf < 4; ++rf) {
#pragma unroll
            for (int r = 0; r < 4; ++r) {
                int rloc = rf * 16 + q * 4 + r;
                float v = acc[ct][rf][r];
                Th[rloc * TH_STRIDE + colb] = f2bf(v);
                if (node0 + rloc < N) { sv += v; qv = fmaf(v, v, qv); }
            }
        }
        sv += __shfl_down(sv, 16); sv += __shfl_down(sv, 32);
        qv += __shfl_down(qv, 16); qv += __shfl_down(qv, 32);
        if (q == 0) { sls[colb] = sv; slq[colb] = qv; }
    }
    __syncthreads();
    int rows = N - node0; if (rows > 64) rows = 64;
    uint2* dstp = (uint2*)(h16g + (size_t)node0 * HID);
    const uint2* srcp = (const uint2*)Th;        // row stride 33 uint2 (132 shorts)
    for (int i = t; i < rows * 32; i += 256) {
        int row = i >> 5, c = i & 31;
        dstp[i] = srcp[row * 33 + c];
    }
    if (t < 128) {
        atomicAdd(&bnsums[t], sls[t]);
        atomicAdd(&bnsums[128 + t], slq[t]);
    }
}

// ===== fused MLP layers 2/3: SINGLE LDS buffer (35KB -> 4 blocks/CU) =====
// schedule: stage T -> sync -> mfma(T,W1) -> sync -> relu/pack in place -> sync
//           -> mfma(T,W2) -> sync -> epilogue (bounce aliases T)
__global__ __launch_bounds__(256) void mlp128_fused(
    const unsigned* __restrict__ Ap,
    const unsigned short* __restrict__ W1h, const unsigned short* __restrict__ W1l,
    const float* __restrict__ b1,
    const unsigned short* __restrict__ W2h, const unsigned short* __restrict__ W2l,
    const float* __restrict__ b2,
    unsigned short* __restrict__ h16g, float* __restrict__ bnsums, int N)
{
    __shared__ unsigned T[64 * 132];
    __shared__ float sls[128], slq[128];
    int t = threadIdx.x;
    int wave = t >> 6, lane = t & 63;
    int q = lane >> 4, li = lane & 15;
    int node0 = blockIdx.x * 64;

    // ---- stage A (already packed): straight uint4 copy global -> padded LDS ----
    {
        const uint4* A4 = (const uint4*)(Ap + (size_t)node0 * HID);
        int rows = N - node0 < 64 ? (N - node0) : 64;
        int limit4 = 32 * rows;
#pragma unroll
        for (int i = 0; i < 8; ++i) {
            int idx = t + i * 256;
            uint4 v = {0u, 0u, 0u, 0u};
            if (idx < limit4) v = A4[idx];
            int row = idx >> 5, c4 = idx & 31;
            *(uint4*)(T + row * 132 + c4 * 4) = v;
        }
    }
    __syncthreads();

    // ---- phase 1: T @ W1 into regs ----
    f32x4 acc1[2][4];
    mfma_core(T, W1h, W1l, b1, wave, q, li, acc1);
    __syncthreads();            // all waves done reading T

    // ---- relu + hi/lo pack written back in place ----
#pragma unroll
    for (int ct = 0; ct < 2; ++ct) {
        int colb = (wave * 2 + ct) * 16 + li;
#pragma unroll
        for (int rf = 0; rf < 4; ++rf) {
#pragma unroll
            for (int r = 0; r < 4; ++r) {
                float v = fmaxf(acc1[ct][rf][r], 0.f);
                T[(rf * 16 + q * 4 + r) * 132 + colb] = packhl(v);
            }
        }
    }
    __syncthreads();

    // ---- phase 2: T @ W2 -> h16 (+stats); bounce buffer aliases T ----
    {
        f32x4 acc[2][4];
        mfma_core(T, W2h, W2l, b2, wave, q, li, acc);
        __syncthreads();        // all waves done reading T before bounce overwrite
        epilogue_h16(acc, h16g, bnsums, sls, slq, (unsigned short*)T,
                     node0, wave, q, li, t, N);
    }
}

// ===== fused MLP layer 1: K=7 fp32 vector (x+agg7) -> packed T, then MFMA =====
// single LDS buffer: Th bounce aliases T (sync before epilogue)
__global__ __launch_bounds__(256) void mlp1_fused(
    const float* __restrict__ x, const float* __restrict__ agg,
    const float* __restrict__ W1, const float* __restrict__ b1,     // [7][128]
    const unsigned short* __restrict__ W2h, const unsigned short* __restrict__ W2l,
    const float* __restrict__ b2,
    unsigned short* __restrict__ h16g, float* __restrict__ bnsums, int N)
{
    __shared__ unsigned T[64 * 132];
    __shared__ float sls[128], slq[128];
    int t = threadIdx.x;
    int wave = t >> 6, lane = t & 63;
    int q = lane >> 4, li = lane & 15;
    int node0 = blockIdx.x * 64;

    // phase 1: rows wave*16+li (4 waves cover 64 rows), q covers col-groups of 32
    {
        int row = node0 + wave * 16 + li;
        bool ok = row < N;
        float xa[7];
#pragma unroll
        for (int k = 0; k < 7; ++k) xa[k] = ok ? (x[row * 7 + k] + agg[row * 7 + k]) : 0.f;
        const float4* W14 = (const float4*)W1;
        const float4* b14 = (const float4*)b1;
        unsigned* Trow = T + (wave * 16 + li) * 132 + q * 32;
#pragma unroll
        for (int c4 = 0; c4 < 8; ++c4) {
            float4 v = b14[q * 8 + c4];
#pragma unroll
            for (int k = 0; k < 7; ++k) {
                float4 w = W14[k * 32 + q * 8 + c4];
                v.x = fmaf(xa[k], w.x, v.x);
                v.y = fmaf(xa[k], w.y, v.y);
                v.z = fmaf(xa[k], w.z, v.z);
                v.w = fmaf(xa[k], w.w, v.w);
            }
            uint4 pk;
            pk.x = packhl(fmaxf(v.x, 0.f));
            pk.y = packhl(fmaxf(v.y, 0.f));
            pk.z = packhl(fmaxf(v.z, 0.f));
            pk.w = packhl(fmaxf(v.w, 0.f));
            *(uint4*)(Trow + c4 * 4) = pk;
        }
    }
    __syncthreads();

    // phase 2
    {
        f32x4 acc[2][4];
        mfma_core(T, W2h, W2l, b2, wave, q, li, acc);
        __syncthreads();        // T reads done before Th bounce overwrites it
        epilogue_h16(acc, h16g, bnsums, sls, slq, (unsigned short*)T,
                     node0, wave, q, li, t, N);
    }
}

// ===== layer-3 BN-apply + mean-pool from bf16 h16 (batch sorted, segmented) =====
__global__ __launch_bounds__(256) void bn_pool(
    const unsigned short* __restrict__ h16, const float* __restrict__ sums,
    const float* __restrict__ g, const float* __restrict__ bt,
    const int* __restrict__ batch,
    float* __restrict__ pools, float* __restrict__ cnt, int Nn)
{
    __shared__ float as_[128], bs_[128];
    int t = threadIdx.x;
    if (t < 128) {
        float inv = 1.f / (float)Nn;
        float mu = sums[t] * inv;
        float var = sums[128 + t] * inv - mu * mu;
        float rs = rsqrtf(fmaxf(var, 0.f) + 1e-5f);
        float a = g[t] * rs;
        as_[t] = a;
        bs_[t] = bt[t] - a * mu;
    }
    __syncthreads();
    int half = t >> 7;
    int c = t & 127;
    int base = blockIdx.x * 64 + half * 32;
    if (base >= Nn) return;
    int lim = base + 32 < Nn ? base + 32 : Nn;
    int g0 = batch[base];
    float s = 0.f, ncnt = 0.f;
    for (int n = base; n < lim; ++n) {
        int gg = batch[n];
        if (gg != g0) {
            atomicAdd(&pools[(size_t)g0 * HID + c], s);
            if (c == 0) atomicAdd(&cnt[g0], ncnt);
            s = 0.f; ncnt = 0.f; g0 = gg;
        }
        float hraw = bf2f(h16[(size_t)n * HID + c]);
        float v = fmaxf(fmaf(hraw, as_[c], bs_[c]), 0.f);
        s += v;
        ncnt += 1.f;
    }
    atomicAdd(&pools[(size_t)g0 * HID + c], s);
    if (c == 0) atomicAdd(&cnt[g0], ncnt);
}

__global__ void head_kernel(const float* __restrict__ pools, const float* __restrict__ cnt,
                            const float* __restrict__ Wf1, const float* __restrict__ bf1,
                            const float* __restrict__ Wf2, const float* __restrict__ bf2,
                            float* __restrict__ out, int G)
{
    int g = blockIdx.x;
    int t = threadIdx.x;
    __shared__ float p[128];
    float inv = 1.f / fmaxf(cnt[g], 1.f);
    p[t] = pools[g * 128 + t] * inv;
    p[t + 64] = pools[g * 128 + t + 64] * inv;
    __syncthreads();
    float o = bf1[t];
#pragma unroll 8
    for (int k = 0; k < 128; ++k) o = fmaf(p[k], Wf1[k * 64 + t], o);
    o = fmaxf(o, 0.f);
    float prod = o * Wf2[t];
#pragma unroll
    for (int off = 32; off > 0; off >>= 1) prod += __shfl_down(prod, off);
    if (t == 0) out[g] = prod + bf2[0];
}

extern "C" void kernel_launch(void* const* d_in, const int* in_sizes, int n_in,
                              void* d_out, int out_size, void* d_ws, size_t ws_size,
                              hipStream_t stream)
{
    const float* x     = (const float*)d_in[0];
    const float* ea    = (const float*)d_in[1];
    const int*   eidx  = (const int*)d_in[2];
    const int*   batch = (const int*)d_in[3];
    const float* We1 = (const float*)d_in[4];  const float* be1 = (const float*)d_in[5];
    const float* W11 = (const float*)d_in[6];  const float* b11 = (const float*)d_in[7];
    const float* W12 = (const float*)d_in[8];  const float* b12 = (const float*)d_in[9];
    const float* g1  = (const float*)d_in[10]; const float* bt1 = (const float*)d_in[11];
    const float* We2 = (const float*)d_in[12]; const float* be2 = (const float*)d_in[13];
    const float* W21 = (const float*)d_in[14]; const float* b21 = (const float*)d_in[15];
    const float* W22 = (const float*)d_in[16]; const float* b22 = (const float*)d_in[17];
    const float* g2  = (const float*)d_in[18]; const float* bt2 = (const float*)d_in[19];
    const float* We3 = (const float*)d_in[20]; const float* be3 = (const float*)d_in[21];
    const float* W31 = (const float*)d_in[22]; const float* b31 = (const float*)d_in[23];
    const float* W32 = (const float*)d_in[24]; const float* b32 = (const float*)d_in[25];
    const float* g3  = (const float*)d_in[26]; const float* bt3 = (const float*)d_in[27];
    const float* Wf1 = (const float*)d_in[28]; const float* bf1 = (const float*)d_in[29];
    const float* Wf2 = (const float*)d_in[30]; const float* bf2 = (const float*)d_in[31];

    const int N = in_sizes[0] / 7;
    const int E = in_sizes[1] / 3;
    const int G = out_size;
    const int* src = eidx;
    const int* dst = eidx + E;

    float* ws = (float*)d_ws;
    float4* stage    = (float4*)ws;                          // E float4 (sort staging)
    int*    sdst     = (int*)(stage + E);                    // E ints
    unsigned* aggp   = (unsigned*)(sdst + E);                // N*128 packed hi/lo agg
    float* agg7      = (float*)(aggp + (size_t)N * HID);     // N*7
    float* bnsums    = agg7 + (size_t)N * 7;                 // 3 x 256
    float* pools     = bnsums + 768;                         // G*128
    float* cntp      = pools + (size_t)G * HID;              // G
    size_t fused     = (size_t)(cntp + G - ws);
    fused = (fused + 3) & ~(size_t)3;                        // 16B align for epack
    float4* epack    = (float4*)(ws + fused);                // E float4
    unsigned short* h16 = (unsigned short*)(epack + E);      // N*128 bf16 (pre-BN h)
    int*   icnt      = (int*)(h16 + (size_t)N * HID);        // N
    int*   ioffs     = icnt + N;                             // N+1
    int*   ibcur     = ioffs + N + 1;                        // 256 (bucket slice cursors)
    int*   ipart     = ibcur + 256;                          // 256
    int*   iexcl     = ipart + 256;                          // N
    unsigned short* wt = (unsigned short*)(iexcl + N);       // 5 x 2 x 16384
    unsigned short* w12h = wt;            unsigned short* w12l = wt + 16384;
    unsigned short* w21h = wt + 32768;    unsigned short* w21l = wt + 49152;
    unsigned short* w22h = wt + 65536;    unsigned short* w22l = wt + 81920;
    unsigned short* w31h = wt + 98304;    unsigned short* w31l = wt + 114688;
    unsigned short* w32h = wt + 131072;   unsigned short* w32l = wt + 147456;

    const unsigned grid_mfma = (unsigned)((N + 63) / 64);
    const unsigned nb_scan   = (unsigned)((N + 255) / 256);
    const unsigned grid_gather = (unsigned)((N + 3) / 4);
    const unsigned grid_gat7 = (unsigned)(((long long)N * 8 + 255) / 256);
    const unsigned grid_pool = (unsigned)((N + 63) / 64);
    const unsigned grid_part = (unsigned)((E + CHUNK - 1) / CHUNK);
    const unsigned grid_buck = (unsigned)((N + 255) / 256);
    const long long PZ = (long long)G * HID + G;

    // ---------- preamble: W splits + zeros + histogram (one launch) ----------
    hipMemsetAsync(icnt, 0, (size_t)N * sizeof(int), stream);
    fused_pre<<<1122, 256, 0, stream>>>(W12, W21, W22, W31, W32, wt,
                                        bnsums, pools, PZ, dst, icnt, E);

    // ---------- CSR offsets + two-phase edge sort ----------
    scan_block<<<nb_scan, 256, 0, stream>>>(icnt, iexcl, ipart, N);
    scan_addf<<<nb_scan, 256, 0, stream>>>(iexcl, ipart, (int)nb_scan, ioffs, ibcur, N, E);
    epart<<<grid_part, 256, 0, stream>>>(dst, src, ea, ibcur, stage, sdst, E);
    elocal<<<grid_buck, 256, 0, stream>>>(stage, sdst, ioffs, epack, N);

    // ---------- layer 1 ----------
    gather_d7<<<grid_gat7, 256, 0, stream>>>(x, epack, ioffs, We1, be1, agg7, N);
    mlp1_fused<<<grid_mfma, 256, 0, stream>>>(x, agg7, W11, b11, w12h, w12l, b12,
                                              h16, bnsums, N);

    // ---------- layer 2 ----------
    gather_d128<<<grid_gather, 256, 0, stream>>>(h16, epack, ioffs, We2, be2,
                                                 bnsums, g1, bt1, aggp, N);
    mlp128_fused<<<grid_mfma, 256, 0, stream>>>(aggp, w21h, w21l, b21, w22h, w22l, b22,
                                                h16, bnsums + 256, N);

    // ---------- layer 3 ----------
    gather_d128<<<grid_gather, 256, 0, stream>>>(h16, epack, ioffs, We3, be3,
                                                 bnsums + 256, g2, bt2, aggp, N);
    mlp128_fused<<<grid_mfma, 256, 0, stream>>>(aggp, w31h, w31l, b31, w32h, w32l, b32,
                                                h16, bnsums + 512, N);

    // ---------- BN-apply + segmented pool + head ----------
    bn_pool<<<grid_pool, 256, 0, stream>>>(h16, bnsums + 512, g3, bt3, batch,
                                           pools, cntp, N);
    head_kernel<<<G, 64, 0, stream>>>(pools, cntp, Wf1, bf1, Wf2, bf2, (float*)d_out, G);
}